// Round 14
// baseline (4281.939 us; speedup 1.0000x reference)
//
#include <hip/hip_runtime.h>
#include <hip/hip_bf16.h>

typedef __bf16 bf16x8 __attribute__((ext_vector_type(8)));
typedef float  f32x4  __attribute__((ext_vector_type(4)));
typedef int    i32x4  __attribute__((ext_vector_type(4)));

#define BM 256
#define BN 256
#define BK 64           // int8 K-tile; 64-B rows; LDS = 64 KiB -> 2 blocks/CU
#define THREADS 512

__device__ __forceinline__ void gload_lds16(const void* g, void* l) {
  __builtin_amdgcn_global_load_lds(
      (const __attribute__((address_space(1))) void*)g,
      (__attribute__((address_space(3))) void*)l, 16, 0, 0);
}

// Bare counted waits (round-6 lesson: ":::memory" clobber => conservative
// vmcnt(0) drain). Ordering vs C++ code pinned with sched_barrier(0).
template<int N> __device__ __forceinline__ void vmwait() {
  if constexpr (N == 0)      asm volatile("s_waitcnt vmcnt(0)");
  else if constexpr (N == 4) asm volatile("s_waitcnt vmcnt(4)");
}

__device__ __forceinline__ void tile_barrier() {
  __builtin_amdgcn_sched_barrier(0);
  asm volatile("s_barrier");
  __builtin_amdgcn_sched_barrier(0);
}

// ---- per-row x quantization: sx = rowmax/127, q = rne(x/sx), rowsum = sum q ----
__global__ __launch_bounds__(256)
void quant_x(const float* __restrict__ x, signed char* __restrict__ xq,
             float* __restrict__ sx, int* __restrict__ rowsum, int K) {
  const int row = blockIdx.x, tid = threadIdx.x;
  const int wave = tid >> 6, lane = tid & 63;
  const float* xr = x + (long)row * K;
  __shared__ float smax[4];
  __shared__ int   ssum[4];

  float amax = 0.f;
  for (int i = tid * 16; i < K; i += 256 * 16) {
    #pragma unroll
    for (int j = 0; j < 4; ++j) {
      float4 v = *(const float4*)(xr + i + j * 4);
      amax = fmaxf(amax, fmaxf(fmaxf(fabsf(v.x), fabsf(v.y)),
                               fmaxf(fabsf(v.z), fabsf(v.w))));
    }
  }
  #pragma unroll
  for (int m = 32; m >= 1; m >>= 1) amax = fmaxf(amax, __shfl_xor(amax, m));
  if (lane == 0) smax[wave] = amax;
  __syncthreads();
  const float m4 = fmaxf(fmaxf(smax[0], smax[1]), fmaxf(smax[2], smax[3]));
  const float scale = (m4 > 0.f) ? (m4 / 127.f) : 1.f;
  const float inv   = (m4 > 0.f) ? (127.f / m4) : 0.f;

  int lsum = 0;
  for (int i = tid * 16; i < K; i += 256 * 16) {
    union { signed char c[16]; int4 v; } u;
    #pragma unroll
    for (int j = 0; j < 4; ++j) {
      float4 v = *(const float4*)(xr + i + j * 4);
      int q0 = __float2int_rn(v.x * inv), q1 = __float2int_rn(v.y * inv);
      int q2 = __float2int_rn(v.z * inv), q3 = __float2int_rn(v.w * inv);
      u.c[j*4+0] = (signed char)q0; u.c[j*4+1] = (signed char)q1;
      u.c[j*4+2] = (signed char)q2; u.c[j*4+3] = (signed char)q3;
      lsum += q0 + q1 + q2 + q3;
    }
    *(int4*)(xq + (long)row * K + i) = u.v;
  }
  #pragma unroll
  for (int m = 32; m >= 1; m >>= 1) lsum += __shfl_xor(lsum, m);
  if (lane == 0) ssum[wave] = lsum;
  __syncthreads();
  if (tid == 0) {
    rowsum[row] = ssum[0] + ssum[1] + ssum[2] + ssum[3];
    sx[row] = scale;
  }
}

// ---- (int32 weight - zp) -> int8 (exact for the symmetric-quant data) ----
__global__ void conv_w(const int* __restrict__ w, const int* __restrict__ zp,
                       signed char* __restrict__ wq, int K, long n) {
  long i0 = ((long)blockIdx.x * blockDim.x + threadIdx.x) * 16;
  long stride = (long)gridDim.x * blockDim.x * 16;
  for (long i = i0; i < n; i += stride) {
    const int z = zp[i / K];
    union { signed char c[16]; int4 v; } u;
    #pragma unroll
    for (int j = 0; j < 4; ++j) {
      int4 a = *(const int4*)(w + i + j * 4);
      int q0 = min(127, max(-128, a.x - z)), q1 = min(127, max(-128, a.y - z));
      int q2 = min(127, max(-128, a.z - z)), q3 = min(127, max(-128, a.w - z));
      u.c[j*4+0] = (signed char)q0; u.c[j*4+1] = (signed char)q1;
      u.c[j*4+2] = (signed char)q2; u.c[j*4+3] = (signed char)q3;
    }
    *(int4*)(wq + i) = u.v;
  }
}

// ====== int8 256x256 GEMM, BK=64, 64 KiB LDS -> TWO blocks per CU ======
// Rounds 7-13: every schedule (burst / phased / sw-pipelined / T19-pinned)
// landed at the serial pipe sum. Root cause finally identified via
// OccupancyPercent=22%: 128 KiB LDS = ONE block/CU, so all 8 waves share one
// barrier group -> during read-bursts/staging there is no independent wave to
// feed the MFMA pipe. Fix: BK 128->64 halves LDS to 64 KiB -> 2 co-resident
// blocks (m114 mechanism: their barrier groups drift, block A's MFMA covers
// block B's reads/staging).
// Swizzle for 64-B rows (4x16B slots): slot' = ks ^ ((row>>1)&3). For each
// 16-lane b128 group: bank-window = 4(row&1) + slot' -> all 8 windows used
// exactly 2x = conflict-free minimum (m136: 2-way free). Staging chunk =
// 16 rows = 1 KiB; lane l -> row l>>2, slot l&3; pre-swizzled source slot =
// (l&3)^((l>>3)&3)  (same involution: (row>>1)&3 = (l>>3)&3, chunk base %4==0).
// Sync per tile: tile_barrier(i); 4x gload_lds t+2 -> buf b; vmcnt(4);
// tile_barrier(ii). RAW: outstanding at vmcnt = t+1's 4 + t+2's 4. WAR: all
// reads of buf b feed MFMAs above barrier (i). Tails peeled branch-free.
// Epilogue: out = sx[r]*sw[c]*(acc - zp[c]*rowsum[r]) + bias[c]  (zp exact).
__global__ __launch_bounds__(THREADS, 4)
void qlin_gemm_i8(const signed char* __restrict__ A, const signed char* __restrict__ B,
                  const float* __restrict__ sx, const int* __restrict__ rowsum,
                  const int* __restrict__ zp,
                  const float* __restrict__ scale, const float* __restrict__ bias,
                  float* __restrict__ C, int M, int N, int K) {
  __shared__ alignas(16) signed char As[2][BM * BK];   // 2 x 16 KiB
  __shared__ alignas(16) signed char Bs[2][BN * BK];   // 2 x 16 KiB

  const int tid  = threadIdx.x;
  const int wave = tid >> 6;
  const int lane = tid & 63;
  const int wm = wave >> 2, wn = wave & 3;       // 2x4 waves; per-wave 128x64

  int bid = blockIdx.x, nwg = gridDim.x, swz = bid;
  if ((nwg & 7) == 0) swz = (bid & 7) * (nwg >> 3) + (bid >> 3);
  const int ntn = N / BN;
  const long row0 = (long)(swz / ntn) * BM;
  const long col0 = (long)(swz % ntn) * BN;

  const signed char* Ag = A + row0 * (long)K;
  const signed char* Bg = B + col0 * (long)K;

  // staging: chunk c = rows [c*16, c*16+16) (1 KiB). Wave w stages chunks
  // {w, w+8} of A and of B. HW: lane l -> chunkbase + l*16.
  const int srow = lane >> 2;                           // row within chunk
  const int kswz = ((lane & 3) ^ ((lane >> 3) & 3)) * 16; // pre-swizzled bytes

#define STAGE_A(b, c, kt) gload_lds16(Ag + (long)((c)*16 + srow) * K + (kt) + kswz, \
                                      &As[b][(c)*1024])
#define STAGE_B(b, c, kt) gload_lds16(Bg + (long)((c)*16 + srow) * K + (kt) + kswz, \
                                      &Bs[b][(c)*1024])
#define STAGE4(b, kt) { STAGE_B(b, wave, kt); STAGE_B(b, wave + 8, kt); \
                        STAGE_A(b, wave, kt); STAGE_A(b, wave + 8, kt); }

  const int rsel = lane & 15;     // fragment row (within 16)
  const int ksl  = lane >> 4;     // 0..3 -> 16B k-slot within K=64
  const int rdx  = ((ksl ^ ((rsel >> 1) & 3)) << 4);  // swizzled slot offset

  i32x4 acc[8][4] = {};
  i32x4 bf[4];                    // B frags, live across one tile

#define AF_READ(bb, m) \
  (*(const i32x4*)&As[bb][(wm*128 + (m)*16 + rsel)*BK + rdx])

#define TILE(bb, STAGES, ENDW)                                                   \
  {                                                                              \
    __builtin_amdgcn_s_setprio(1);                                               \
    _Pragma("unroll")                                                            \
    for (int n = 0; n < 4; ++n)                                                  \
      bf[n] = *(const i32x4*)&Bs[bb][(wn*64 + n*16 + rsel)*BK + rdx];            \
    i32x4 afp0, afp1;                                                            \
    afp0 = AF_READ(bb, 0);                                                       \
    _Pragma("unroll")                                                            \
    for (int f = 0; f < 8; ++f) {                                                \
      if (f < 7) {                                                               \
        if (f & 1) afp0 = AF_READ(bb, f + 1);                                    \
        else       afp1 = AF_READ(bb, f + 1);                                    \
      }                                                                          \
      _Pragma("unroll")                                                          \
      for (int n = 0; n < 4; ++n)                                                \
        acc[f][n] = __builtin_amdgcn_mfma_i32_16x16x64_i8(                       \
            (f & 1) ? afp1 : afp0, bf[n], acc[f][n], 0, 0, 0);                   \
    }                                                                            \
    __builtin_amdgcn_s_setprio(0);                                               \
    tile_barrier();  /* (i) */                                                   \
    STAGES;                                                                      \
    ENDW;                                                                        \
    tile_barrier();  /* (ii) */                                                  \
  }

  const int NT = K / BK;   // 64 for this shape; even, >= 6 (guarded)

  // Prologue: stage tile0 -> buf0, tile1 -> buf1; land tile0 before entering.
  STAGE4(0, 0)
  STAGE4(1, BK)
  vmwait<4>();                       // tile0's 4 retired; tile1's 4 in flight
  tile_barrier();

  // Steady: pairs (t, t+1), literal bufs (0,1); tile t stages t+2.
  for (int t = 0; t < NT - 3; t += 2) {
    const long kt2 = (long)(t + 2) * BK;
    const long kt3 = (long)(t + 3) * BK;
    TILE(0, STAGE4(0, kt2), vmwait<4>())
    TILE(1, STAGE4(1, kt3), vmwait<4>())
  }
  TILE(0, (void)0, vmwait<0>())      // tile NT-2: drain tile NT-1's batch
  TILE(1, (void)0, (void)0)          // tile NT-1: pure compute
#undef TILE
#undef AF_READ
#undef STAGE4
#undef STAGE_A
#undef STAGE_B

  // Epilogue. C/D layout (dtype-independent, m121-128): col = lane&15,
  // row = (lane>>4)*4 + j.  out = sx*sw*(acc - zp*rowsum) + bias.
  float swv[4], bvv[4]; int zpv[4];
  #pragma unroll
  for (int n = 0; n < 4; ++n) {
    const long gcol = col0 + wn * 64 + n * 16 + rsel;
    swv[n] = scale[gcol];
    bvv[n] = bias[gcol];
    zpv[n] = zp[gcol];
  }
  #pragma unroll
  for (int m = 0; m < 8; ++m) {
    const long growb = row0 + wm * 128 + m * 16 + ksl * 4;
    #pragma unroll
    for (int j = 0; j < 4; ++j) {
      const long grow = growb + j;
      const float sxv = sx[grow];
      const int   rsv = rowsum[grow];
      float* orow = C + grow * (long)N;
      #pragma unroll
      for (int n = 0; n < 4; ++n) {
        const long gcol = col0 + wn * 64 + n * 16 + rsel;
        orow[gcol] = (float)(acc[m][n][j] - zpv[n] * rsv) * (sxv * swv[n]) + bvv[n];
      }
    }
  }
}

// ---- fallback (ws too small / odd shape): reg-staged 128x128 bf16, inline dequant ----
__global__ __launch_bounds__(256)
void qlin_gemm_small(const float* __restrict__ Af, const int* __restrict__ Bi,
                     const int* __restrict__ zp,
                     const float* __restrict__ scale, const float* __restrict__ bias,
                     float* __restrict__ C, int M, int N, int K) {
  __shared__ alignas(16) __bf16 As[128 * 64];
  __shared__ alignas(16) __bf16 Bs[128 * 64];
  const int tid = threadIdx.x, wave = tid >> 6, lane = tid & 63;
  int bid = blockIdx.x, nwg = gridDim.x, swz = bid;
  if ((nwg & 7) == 0) swz = (bid & 7) * (nwg >> 3) + (bid >> 3);
  const int ntn = N / 128;
  const long row0 = (long)(swz / ntn) * 128, col0 = (long)(swz % ntn) * 128;
  const int wr = wave >> 1, wc = wave & 1;
  f32x4 acc[4][4] = {};
  for (int kt = 0; kt < K; kt += 64) {
    #pragma unroll
    for (int i = 0; i < 4; ++i) {
      const int flat = i * 2048 + tid * 8;
      const int r = flat >> 6, cc = flat & 63;
      const int wcc = ((cc >> 3) ^ (r & 7)) << 3;
      const float* g = Af + (row0 + r) * (long)K + kt + cc;
      float4 f0 = *(const float4*)g; float4 f1 = *(const float4*)(g + 4);
      bf16x8 v;
      v[0]=(__bf16)f0.x; v[1]=(__bf16)f0.y; v[2]=(__bf16)f0.z; v[3]=(__bf16)f0.w;
      v[4]=(__bf16)f1.x; v[5]=(__bf16)f1.y; v[6]=(__bf16)f1.z; v[7]=(__bf16)f1.w;
      *(bf16x8*)(As + r * 64 + wcc) = v;
    }
    #pragma unroll
    for (int i = 0; i < 4; ++i) {
      const int flat = i * 2048 + tid * 8;
      const int r = flat >> 6, cc = flat & 63;
      const int wcc = ((cc >> 3) ^ (r & 7)) << 3;
      const long grow = col0 + r;
      const int z = zp[grow];
      const int* g = Bi + grow * (long)K + kt + cc;
      int4 a = *(const int4*)g; int4 b = *(const int4*)(g + 4);
      bf16x8 v;
      v[0]=(__bf16)(float)(a.x-z); v[1]=(__bf16)(float)(a.y-z);
      v[2]=(__bf16)(float)(a.z-z); v[3]=(__bf16)(float)(a.w-z);
      v[4]=(__bf16)(float)(b.x-z); v[5]=(__bf16)(float)(b.y-z);
      v[6]=(__bf16)(float)(b.z-z); v[7]=(__bf16)(float)(b.w-z);
      *(bf16x8*)(Bs + r * 64 + wcc) = v;
    }
    __syncthreads();
    #pragma unroll
    for (int kk = 0; kk < 2; ++kk) {
      bf16x8 af[4], bfr[4];
      const int rs = lane & 15, ks = kk * 4 + (lane >> 4);
      const int rd = (ks ^ (lane & 7)) << 3;
      #pragma unroll
      for (int m = 0; m < 4; ++m) af[m] = *(const bf16x8*)(As + (wr*64 + m*16 + rs)*64 + rd);
      #pragma unroll
      for (int n = 0; n < 4; ++n) bfr[n] = *(const bf16x8*)(Bs + (wc*64 + n*16 + rs)*64 + rd);
      #pragma unroll
      for (int m = 0; m < 4; ++m)
        #pragma unroll
        for (int n = 0; n < 4; ++n)
          acc[m][n] = __builtin_amdgcn_mfma_f32_16x16x32_bf16(af[m], bfr[n], acc[m][n], 0, 0, 0);
    }
    __syncthreads();
  }
  #pragma unroll
  for (int m = 0; m < 4; ++m) {
    const long grow = row0 + wr * 64 + m * 16 + ((lane >> 4) << 2);
    #pragma unroll
    for (int n = 0; n < 4; ++n) {
      const long gcol = col0 + wc * 64 + n * 16 + (lane & 15);
      const float s = scale[gcol], bb2 = bias[gcol];
      float* o = C + grow * (long)N + gcol;
      #pragma unroll
      for (int j = 0; j < 4; ++j) o[(long)j * N] = acc[m][n][j] * s + bb2;
    }
  }
}

extern "C" void kernel_launch(void* const* d_in, const int* in_sizes, int n_in,
                              void* d_out, int out_size, void* d_ws, size_t ws_size,
                              hipStream_t stream) {
  const float* x    = (const float*)d_in[0];
  const int*   wint = (const int*)d_in[1];
  const float* wsc  = (const float*)d_in[2];
  const int*   wzp  = (const int*)d_in[3];
  const float* bias = (const float*)d_in[4];
  float* out = (float*)d_out;

  const int N = in_sizes[4];            // 16384 (OUT)
  const int K = in_sizes[1] / N;        // 4096  (IN)
  const int M = in_sizes[0] / K;        // 8192  (B*S)

  const size_t xqb = (size_t)M * K;             // int8 x
  const size_t wqb = (size_t)N * K;             // int8 w
  const size_t sxb = (size_t)M * sizeof(float);
  const size_t rsb = (size_t)M * sizeof(int);
  const int NT = K / BK;

  if (ws_size >= xqb + wqb + sxb + rsb && (M % BM) == 0 && (N % BN) == 0 &&
      (K % BK) == 0 && (K % 4096) == 0 && NT >= 6 && (NT % 2) == 0) {
    signed char* xq = (signed char*)d_ws;
    signed char* wq = xq + xqb;
    float* sx  = (float*)(wq + wqb);
    int* rsum  = (int*)((char*)sx + sxb);
    quant_x<<<M, 256, 0, stream>>>(x, xq, sx, rsum, K);
    conv_w<<<2048, 256, 0, stream>>>(wint, wzp, wq, K, (long)N * K);
    const int grid = (M / BM) * (N / BN); // 32 * 64 = 2048
    qlin_gemm_i8<<<grid, THREADS, 0, stream>>>(xq, wq, sx, rsum, wzp, wsc, bias,
                                               out, M, N, K);
  } else {
    const int grid = (M / 128) * (N / 128);
    qlin_gemm_small<<<grid, 256, 0, stream>>>(x, wint, wzp, wsc, bias, out, M, N, K);
  }
}

// Round 15
// 868.987 us; speedup vs baseline: 4.9275x; 4.9275x over previous
//
#include <hip/hip_runtime.h>
#include <hip/hip_bf16.h>

typedef __bf16 bf16x8 __attribute__((ext_vector_type(8)));
typedef float  f32x4  __attribute__((ext_vector_type(4)));
typedef int    i32x4  __attribute__((ext_vector_type(4)));

#define BM 128
#define BN 128
#define BK 64           // int8 K-tile; 64-B rows; LDS = 32 KiB total
#define THREADS 256

__device__ __forceinline__ void gload_lds16(const void* g, void* l) {
  __builtin_amdgcn_global_load_lds(
      (const __attribute__((address_space(1))) void*)g,
      (__attribute__((address_space(3))) void*)l, 16, 0, 0);
}

// Bare counted waits (round-6 lesson: ":::memory" clobber => conservative
// vmcnt(0) drain).
template<int N> __device__ __forceinline__ void vmwait() {
  if constexpr (N == 0)      asm volatile("s_waitcnt vmcnt(0)");
  else if constexpr (N == 4) asm volatile("s_waitcnt vmcnt(4)");
}

__device__ __forceinline__ void tile_barrier() {
  __builtin_amdgcn_sched_barrier(0);
  asm volatile("s_barrier");
  __builtin_amdgcn_sched_barrier(0);
}

// ---- per-row x quantization: sx = rowmax/127, q = rne(x/sx), rowsum = sum q ----
__global__ __launch_bounds__(256)
void quant_x(const float* __restrict__ x, signed char* __restrict__ xq,
             float* __restrict__ sx, int* __restrict__ rowsum, int K) {
  const int row = blockIdx.x, tid = threadIdx.x;
  const int wave = tid >> 6, lane = tid & 63;
  const float* xr = x + (long)row * K;
  __shared__ float smax[4];
  __shared__ int   ssum[4];

  float amax = 0.f;
  for (int i = tid * 16; i < K; i += 256 * 16) {
    #pragma unroll
    for (int j = 0; j < 4; ++j) {
      float4 v = *(const float4*)(xr + i + j * 4);
      amax = fmaxf(amax, fmaxf(fmaxf(fabsf(v.x), fabsf(v.y)),
                               fmaxf(fabsf(v.z), fabsf(v.w))));
    }
  }
  #pragma unroll
  for (int m = 32; m >= 1; m >>= 1) amax = fmaxf(amax, __shfl_xor(amax, m));
  if (lane == 0) smax[wave] = amax;
  __syncthreads();
  const float m4 = fmaxf(fmaxf(smax[0], smax[1]), fmaxf(smax[2], smax[3]));
  const float scale = (m4 > 0.f) ? (m4 / 127.f) : 1.f;
  const float inv   = (m4 > 0.f) ? (127.f / m4) : 0.f;

  int lsum = 0;
  for (int i = tid * 16; i < K; i += 256 * 16) {
    union { signed char c[16]; int4 v; } u;
    #pragma unroll
    for (int j = 0; j < 4; ++j) {
      float4 v = *(const float4*)(xr + i + j * 4);
      int q0 = __float2int_rn(v.x * inv), q1 = __float2int_rn(v.y * inv);
      int q2 = __float2int_rn(v.z * inv), q3 = __float2int_rn(v.w * inv);
      u.c[j*4+0] = (signed char)q0; u.c[j*4+1] = (signed char)q1;
      u.c[j*4+2] = (signed char)q2; u.c[j*4+3] = (signed char)q3;
      lsum += q0 + q1 + q2 + q3;
    }
    *(int4*)(xq + (long)row * K + i) = u.v;
  }
  #pragma unroll
  for (int m = 32; m >= 1; m >>= 1) lsum += __shfl_xor(lsum, m);
  if (lane == 0) ssum[wave] = lsum;
  __syncthreads();
  if (tid == 0) {
    rowsum[row] = ssum[0] + ssum[1] + ssum[2] + ssum[3];
    sx[row] = scale;
  }
}

// ---- (int32 weight - zp) -> int8 (exact for the symmetric-quant data) ----
__global__ void conv_w(const int* __restrict__ w, const int* __restrict__ zp,
                       signed char* __restrict__ wq, int K, long n) {
  long i0 = ((long)blockIdx.x * blockDim.x + threadIdx.x) * 16;
  long stride = (long)gridDim.x * blockDim.x * 16;
  for (long i = i0; i < n; i += stride) {
    const int z = zp[i / K];
    union { signed char c[16]; int4 v; } u;
    #pragma unroll
    for (int j = 0; j < 4; ++j) {
      int4 a = *(const int4*)(w + i + j * 4);
      int q0 = min(127, max(-128, a.x - z)), q1 = min(127, max(-128, a.y - z));
      int q2 = min(127, max(-128, a.z - z)), q3 = min(127, max(-128, a.w - z));
      u.c[j*4+0] = (signed char)q0; u.c[j*4+1] = (signed char)q1;
      u.c[j*4+2] = (signed char)q2; u.c[j*4+3] = (signed char)q3;
    }
    *(int4*)(wq + i) = u.v;
  }
}

// ====== int8 128x128 GEMM, BK=64, 256 thr, 32 KiB LDS -> 2-3 blocks/CU ======
// Round-14 lesson: co-residency via launch_bounds squeeze (512thr, acc=128
// AGPR, cap 64 VGPR) -> catastrophic spills (WRITE 13 GB). The geometry must
// make co-residency register-FEASIBLE: 128x128 tile / 4 waves / per-wave
// 64x64 -> acc[4][4] = 64 AGPR, ~140 total regs -> 2-3 blocks/CU at natural
// allocation (bounds (256,2): cap 256, no forced squeeze). Independent
// barrier groups per block de-correlate read/MFMA/stage phases (m114/m97 —
// the only overlap mechanism that has worked in rounds 7-13).
// Swizzle (from r14, numerically verified there): LDS[row][slot16B] holds
// k-slot = slot ^ ((row>>1)&3); staging chunk = 16 rows (1 KiB), lane l ->
// row l>>2, slot l&3, pre-swizzled source slot (l&3)^((l>>3)&3); read offset
// rdx = (ksl ^ ((rsel>>1)&3))*16. 2-way bank aliasing = free (m136).
// Sync per tile (r12 skeleton): tile_barrier(i); 4x gload_lds t+2 -> buf b;
// vmcnt(4); tile_barrier(ii). RAW: outstanding at vmcnt = t+1's 4 + t+2's 4.
// WAR: all reads of buf b feed MFMAs above barrier (i). Tails peeled.
// Epilogue: out = sx[r]*sw[c]*(acc - zp[c]*rowsum[r]) + bias[c]  (zp exact).
__global__ __launch_bounds__(THREADS, 2)
void qlin_gemm_i8(const signed char* __restrict__ A, const signed char* __restrict__ B,
                  const float* __restrict__ sx, const int* __restrict__ rowsum,
                  const int* __restrict__ zp,
                  const float* __restrict__ scale, const float* __restrict__ bias,
                  float* __restrict__ C, int M, int N, int K) {
  __shared__ alignas(16) signed char As[2][BM * BK];   // 2 x 8 KiB
  __shared__ alignas(16) signed char Bs[2][BN * BK];   // 2 x 8 KiB

  const int tid  = threadIdx.x;
  const int wave = tid >> 6;
  const int lane = tid & 63;
  const int wm = wave >> 1, wn = wave & 1;       // 2x2 waves; per-wave 64x64

  int bid = blockIdx.x, nwg = gridDim.x, swz = bid;
  if ((nwg & 7) == 0) swz = (bid & 7) * (nwg >> 3) + (bid >> 3);
  const int ntn = N / BN;
  const long row0 = (long)(swz / ntn) * BM;
  const long col0 = (long)(swz % ntn) * BN;

  const signed char* Ag = A + row0 * (long)K;
  const signed char* Bg = B + col0 * (long)K;

  // staging: chunk c = rows [c*16, c*16+16) (1 KiB); 8 chunks per matrix.
  // Wave w stages chunks {w, w+4} of A and of B (4 gload_lds/wave/tile).
  const int srow = lane >> 2;                             // row within chunk
  const int kswz = ((lane & 3) ^ ((lane >> 3) & 3)) * 16; // pre-swizzled bytes

#define STAGE_A(b, c, kt) gload_lds16(Ag + (long)((c)*16 + srow) * K + (kt) + kswz, \
                                      &As[b][(c)*1024])
#define STAGE_B(b, c, kt) gload_lds16(Bg + (long)((c)*16 + srow) * K + (kt) + kswz, \
                                      &Bs[b][(c)*1024])
#define STAGE4(b, kt) { STAGE_B(b, wave, kt); STAGE_B(b, wave + 4, kt); \
                        STAGE_A(b, wave, kt); STAGE_A(b, wave + 4, kt); }

  const int rsel = lane & 15;     // fragment row (within 16)
  const int ksl  = lane >> 4;     // 0..3 -> 16B k-slot within K=64
  const int rdx  = ((ksl ^ ((rsel >> 1) & 3)) << 4);  // swizzled slot offset

  i32x4 acc[4][4] = {};
  i32x4 bf[4];                    // B frags, live across one tile

#define AF_READ(bb, m) \
  (*(const i32x4*)&As[bb][(wm*64 + (m)*16 + rsel)*BK + rdx])

#define TILE(bb, STAGES, ENDW)                                                   \
  {                                                                              \
    __builtin_amdgcn_s_setprio(1);                                               \
    _Pragma("unroll")                                                            \
    for (int n = 0; n < 4; ++n)                                                  \
      bf[n] = *(const i32x4*)&Bs[bb][(wn*64 + n*16 + rsel)*BK + rdx];            \
    i32x4 afp0, afp1;                                                            \
    afp0 = AF_READ(bb, 0);                                                       \
    _Pragma("unroll")                                                            \
    for (int f = 0; f < 4; ++f) {                                                \
      if (f < 3) {                                                               \
        if (f & 1) afp0 = AF_READ(bb, f + 1);                                    \
        else       afp1 = AF_READ(bb, f + 1);                                    \
      }                                                                          \
      _Pragma("unroll")                                                          \
      for (int n = 0; n < 4; ++n)                                                \
        acc[f][n] = __builtin_amdgcn_mfma_i32_16x16x64_i8(                       \
            (f & 1) ? afp1 : afp0, bf[n], acc[f][n], 0, 0, 0);                   \
    }                                                                            \
    __builtin_amdgcn_s_setprio(0);                                               \
    tile_barrier();  /* (i) */                                                   \
    STAGES;                                                                      \
    ENDW;                                                                        \
    tile_barrier();  /* (ii) */                                                  \
  }

  const int NT = K / BK;   // 64 for this shape; even, >= 6 (guarded)

  // Prologue: stage tile0 -> buf0, tile1 -> buf1; land tile0 before entering.
  STAGE4(0, 0)
  STAGE4(1, BK)
  vmwait<4>();                       // tile0's 4 retired; tile1's 4 in flight
  tile_barrier();

  // Steady: pairs (t, t+1), literal bufs (0,1); tile t stages t+2.
  for (int t = 0; t < NT - 3; t += 2) {
    const long kt2 = (long)(t + 2) * BK;
    const long kt3 = (long)(t + 3) * BK;
    TILE(0, STAGE4(0, kt2), vmwait<4>())
    TILE(1, STAGE4(1, kt3), vmwait<4>())
  }
  TILE(0, (void)0, vmwait<0>())      // tile NT-2: drain tile NT-1's batch
  TILE(1, (void)0, (void)0)          // tile NT-1: pure compute
#undef TILE
#undef AF_READ
#undef STAGE4
#undef STAGE_A
#undef STAGE_B

  // Epilogue. C/D layout (dtype-independent, m121-128): col = lane&15,
  // row = (lane>>4)*4 + j.  out = sx*sw*(acc - zp*rowsum) + bias.
  float swv[4], bvv[4]; int zpv[4];
  #pragma unroll
  for (int n = 0; n < 4; ++n) {
    const long gcol = col0 + wn * 64 + n * 16 + rsel;
    swv[n] = scale[gcol];
    bvv[n] = bias[gcol];
    zpv[n] = zp[gcol];
  }
  #pragma unroll
  for (int m = 0; m < 4; ++m) {
    const long growb = row0 + wm * 64 + m * 16 + ksl * 4;
    #pragma unroll
    for (int j = 0; j < 4; ++j) {
      const long grow = growb + j;
      const float sxv = sx[grow];
      const int   rsv = rowsum[grow];
      float* orow = C + grow * (long)N;
      #pragma unroll
      for (int n = 0; n < 4; ++n) {
        const long gcol = col0 + wn * 64 + n * 16 + rsel;
        orow[gcol] = (float)(acc[m][n][j] - zpv[n] * rsv) * (sxv * swv[n]) + bvv[n];
      }
    }
  }
}

// ---- fallback (ws too small / odd shape): reg-staged 128x128 bf16, inline dequant ----
__global__ __launch_bounds__(256)
void qlin_gemm_small(const float* __restrict__ Af, const int* __restrict__ Bi,
                     const int* __restrict__ zp,
                     const float* __restrict__ scale, const float* __restrict__ bias,
                     float* __restrict__ C, int M, int N, int K) {
  __shared__ alignas(16) __bf16 As[128 * 64];
  __shared__ alignas(16) __bf16 Bs[128 * 64];
  const int tid = threadIdx.x, wave = tid >> 6, lane = tid & 63;
  int bid = blockIdx.x, nwg = gridDim.x, swz = bid;
  if ((nwg & 7) == 0) swz = (bid & 7) * (nwg >> 3) + (bid >> 3);
  const int ntn = N / 128;
  const long row0 = (long)(swz / ntn) * 128, col0 = (long)(swz % ntn) * 128;
  const int wr = wave >> 1, wc = wave & 1;
  f32x4 acc[4][4] = {};
  for (int kt = 0; kt < K; kt += 64) {
    #pragma unroll
    for (int i = 0; i < 4; ++i) {
      const int flat = i * 2048 + tid * 8;
      const int r = flat >> 6, cc = flat & 63;
      const int wcc = ((cc >> 3) ^ (r & 7)) << 3;
      const float* g = Af + (row0 + r) * (long)K + kt + cc;
      float4 f0 = *(const float4*)g; float4 f1 = *(const float4*)(g + 4);
      bf16x8 v;
      v[0]=(__bf16)f0.x; v[1]=(__bf16)f0.y; v[2]=(__bf16)f0.z; v[3]=(__bf16)f0.w;
      v[4]=(__bf16)f1.x; v[5]=(__bf16)f1.y; v[6]=(__bf16)f1.z; v[7]=(__bf16)f1.w;
      *(bf16x8*)(As + r * 64 + wcc) = v;
    }
    #pragma unroll
    for (int i = 0; i < 4; ++i) {
      const int flat = i * 2048 + tid * 8;
      const int r = flat >> 6, cc = flat & 63;
      const int wcc = ((cc >> 3) ^ (r & 7)) << 3;
      const long grow = col0 + r;
      const int z = zp[grow];
      const int* g = Bi + grow * (long)K + kt + cc;
      int4 a = *(const int4*)g; int4 b = *(const int4*)(g + 4);
      bf16x8 v;
      v[0]=(__bf16)(float)(a.x-z); v[1]=(__bf16)(float)(a.y-z);
      v[2]=(__bf16)(float)(a.z-z); v[3]=(__bf16)(float)(a.w-z);
      v[4]=(__bf16)(float)(b.x-z); v[5]=(__bf16)(float)(b.y-z);
      v[6]=(__bf16)(float)(b.z-z); v[7]=(__bf16)(float)(b.w-z);
      *(bf16x8*)(Bs + r * 64 + wcc) = v;
    }
    __syncthreads();
    #pragma unroll
    for (int kk = 0; kk < 2; ++kk) {
      bf16x8 af[4], bfr[4];
      const int rs = lane & 15, ks = kk * 4 + (lane >> 4);
      const int rd = (ks ^ (lane & 7)) << 3;
      #pragma unroll
      for (int m = 0; m < 4; ++m) af[m] = *(const bf16x8*)(As + (wr*64 + m*16 + rs)*64 + rd);
      #pragma unroll
      for (int n = 0; n < 4; ++n) bfr[n] = *(const bf16x8*)(Bs + (wc*64 + n*16 + rs)*64 + rd);
      #pragma unroll
      for (int m = 0; m < 4; ++m)
        #pragma unroll
        for (int n = 0; n < 4; ++n)
          acc[m][n] = __builtin_amdgcn_mfma_f32_16x16x32_bf16(af[m], bfr[n], acc[m][n], 0, 0, 0);
    }
    __syncthreads();
  }
  #pragma unroll
  for (int m = 0; m < 4; ++m) {
    const long grow = row0 + wr * 64 + m * 16 + ((lane >> 4) << 2);
    #pragma unroll
    for (int n = 0; n < 4; ++n) {
      const long gcol = col0 + wc * 64 + n * 16 + (lane & 15);
      const float s = scale[gcol], bb2 = bias[gcol];
      float* o = C + grow * (long)N + gcol;
      #pragma unroll
      for (int j = 0; j < 4; ++j) o[(long)j * N] = acc[m][n][j] * s + bb2;
    }
  }
}

extern "C" void kernel_launch(void* const* d_in, const int* in_sizes, int n_in,
                              void* d_out, int out_size, void* d_ws, size_t ws_size,
                              hipStream_t stream) {
  const float* x    = (const float*)d_in[0];
  const int*   wint = (const int*)d_in[1];
  const float* wsc  = (const float*)d_in[2];
  const int*   wzp  = (const int*)d_in[3];
  const float* bias = (const float*)d_in[4];
  float* out = (float*)d_out;

  const int N = in_sizes[4];            // 16384 (OUT)
  const int K = in_sizes[1] / N;        // 4096  (IN)
  const int M = in_sizes[0] / K;        // 8192  (B*S)

  const size_t xqb = (size_t)M * K;             // int8 x
  const size_t wqb = (size_t)N * K;             // int8 w
  const size_t sxb = (size_t)M * sizeof(float);
  const size_t rsb = (size_t)M * sizeof(int);
  const int NT = K / BK;

  if (ws_size >= xqb + wqb + sxb + rsb && (M % BM) == 0 && (N % BN) == 0 &&
      (K % BK) == 0 && (K % 4096) == 0 && NT >= 6 && (NT % 2) == 0) {
    signed char* xq = (signed char*)d_ws;
    signed char* wq = xq + xqb;
    float* sx  = (float*)(wq + wqb);
    int* rsum  = (int*)((char*)sx + sxb);
    quant_x<<<M, 256, 0, stream>>>(x, xq, sx, rsum, K);
    conv_w<<<2048, 256, 0, stream>>>(wint, wzp, wq, K, (long)N * K);
    const int grid = (M / BM) * (N / BN); // 64 * 128 = 8192
    qlin_gemm_i8<<<grid, THREADS, 0, stream>>>(xq, wq, sx, rsum, wzp, wsc, bias,
                                               out, M, N, K);
  } else {
    const int grid = (M / 128) * (N / 128);
    qlin_gemm_small<<<grid, 256, 0, stream>>>(x, wint, wzp, wsc, bias, out, M, N, K);
  }
}

// Round 16
// 848.745 us; speedup vs baseline: 5.0450x; 1.0238x over previous
//
#include <hip/hip_runtime.h>
#include <hip/hip_bf16.h>

typedef __bf16 bf16x8 __attribute__((ext_vector_type(8)));
typedef float  f32x4  __attribute__((ext_vector_type(4)));
typedef int    i32x4  __attribute__((ext_vector_type(4)));

#define BM 128
#define BN 128
#define BK 128          // FULL 128-B rows (r15 lesson: BK=64 => half-line HBM fetch, 2x overfetch)
#define THREADS 256

__device__ __forceinline__ void gload_lds16(const void* g, void* l) {
  __builtin_amdgcn_global_load_lds(
      (const __attribute__((address_space(1))) void*)g,
      (__attribute__((address_space(3))) void*)l, 16, 0, 0);
}

// Bare counted waits (round-6 lesson: ":::memory" clobber => conservative
// vmcnt(0) drain).
template<int N> __device__ __forceinline__ void vmwait() {
  if constexpr (N == 0)      asm volatile("s_waitcnt vmcnt(0)");
  else if constexpr (N == 8) asm volatile("s_waitcnt vmcnt(8)");
}

__device__ __forceinline__ void tile_barrier() {
  __builtin_amdgcn_sched_barrier(0);
  asm volatile("s_barrier");
  __builtin_amdgcn_sched_barrier(0);
}

// ---- per-row x quantization: sx = rowmax/127, q = rne(x/sx), rowsum = sum q ----
__global__ __launch_bounds__(256)
void quant_x(const float* __restrict__ x, signed char* __restrict__ xq,
             float* __restrict__ sx, int* __restrict__ rowsum, int K) {
  const int row = blockIdx.x, tid = threadIdx.x;
  const int wave = tid >> 6, lane = tid & 63;
  const float* xr = x + (long)row * K;
  __shared__ float smax[4];
  __shared__ int   ssum[4];

  float amax = 0.f;
  for (int i = tid * 16; i < K; i += 256 * 16) {
    #pragma unroll
    for (int j = 0; j < 4; ++j) {
      float4 v = *(const float4*)(xr + i + j * 4);
      amax = fmaxf(amax, fmaxf(fmaxf(fabsf(v.x), fabsf(v.y)),
                               fmaxf(fabsf(v.z), fabsf(v.w))));
    }
  }
  #pragma unroll
  for (int m = 32; m >= 1; m >>= 1) amax = fmaxf(amax, __shfl_xor(amax, m));
  if (lane == 0) smax[wave] = amax;
  __syncthreads();
  const float m4 = fmaxf(fmaxf(smax[0], smax[1]), fmaxf(smax[2], smax[3]));
  const float scale = (m4 > 0.f) ? (m4 / 127.f) : 1.f;
  const float inv   = (m4 > 0.f) ? (127.f / m4) : 0.f;

  int lsum = 0;
  for (int i = tid * 16; i < K; i += 256 * 16) {
    union { signed char c[16]; int4 v; } u;
    #pragma unroll
    for (int j = 0; j < 4; ++j) {
      float4 v = *(const float4*)(xr + i + j * 4);
      int q0 = __float2int_rn(v.x * inv), q1 = __float2int_rn(v.y * inv);
      int q2 = __float2int_rn(v.z * inv), q3 = __float2int_rn(v.w * inv);
      u.c[j*4+0] = (signed char)q0; u.c[j*4+1] = (signed char)q1;
      u.c[j*4+2] = (signed char)q2; u.c[j*4+3] = (signed char)q3;
      lsum += q0 + q1 + q2 + q3;
    }
    *(int4*)(xq + (long)row * K + i) = u.v;
  }
  #pragma unroll
  for (int m = 32; m >= 1; m >>= 1) lsum += __shfl_xor(lsum, m);
  if (lane == 0) ssum[wave] = lsum;
  __syncthreads();
  if (tid == 0) {
    rowsum[row] = ssum[0] + ssum[1] + ssum[2] + ssum[3];
    sx[row] = scale;
  }
}

// ---- (int32 weight - zp) -> int8 (exact for the symmetric-quant data) ----
__global__ void conv_w(const int* __restrict__ w, const int* __restrict__ zp,
                       signed char* __restrict__ wq, int K, long n) {
  long i0 = ((long)blockIdx.x * blockDim.x + threadIdx.x) * 16;
  long stride = (long)gridDim.x * blockDim.x * 16;
  for (long i = i0; i < n; i += stride) {
    const int z = zp[i / K];
    union { signed char c[16]; int4 v; } u;
    #pragma unroll
    for (int j = 0; j < 4; ++j) {
      int4 a = *(const int4*)(w + i + j * 4);
      int q0 = min(127, max(-128, a.x - z)), q1 = min(127, max(-128, a.y - z));
      int q2 = min(127, max(-128, a.z - z)), q3 = min(127, max(-128, a.w - z));
      u.c[j*4+0] = (signed char)q0; u.c[j*4+1] = (signed char)q1;
      u.c[j*4+2] = (signed char)q2; u.c[j*4+3] = (signed char)q3;
    }
    *(int4*)(wq + i) = u.v;
  }
}

// ====== int8 128x128 GEMM, BK=128, 256 thr, 64 KiB LDS -> 2 blocks/CU ======
// The clean co-residency test (r15 was confounded by BK=64 half-line HBM
// fetch: hbm 2.8 GB @3.5 TB/s == its whole 780 us). This config:
//  - BK=128: staged row segments are FULL 128-B cache lines (r13's fetch
//    profile, 1.1 GB).
//  - 128x128 tile / 4 waves (2x2) / per-wave 64x64 -> acc[4][4] = 64 AGPR,
//    ~130 total regs -> register-feasible co-residency (r14 lesson).
//  - LDS = 2dbuf x (16+16) KiB = 64 KiB -> 2 blocks/CU = 2 INDEPENDENT
//    barrier groups (m114: block A's MFMA phase covers block B's reads).
// Swizzle = r13's verbatim (verified, absmax 5.0): LDS[row][slot16B] holds
// k-slot = slot ^ (row&7); stage chunk = 32 rows (4 waves x 8 rows, 1 KiB
// per wave-instr), pre-swizzled source slot (lane&7)^(lane>>3); read offset
// ((kk*4+ksl) ^ (rsel&7))*16.
// Sync per tile (r12 skeleton): tile_barrier(i); 8x gload_lds t+2 -> buf b;
// vmcnt(8); tile_barrier(ii). RAW: outstanding at vmcnt = t+1's 8 + t+2's 8
// -> retires t+1 exactly. WAR: all reads of buf b feed MFMAs above (i).
// Tails peeled branch-free (r5 spill lesson).
// Epilogue: out = sx[r]*sw[c]*(acc - zp[c]*rowsum[r]) + bias[c]  (zp exact).
__global__ __launch_bounds__(THREADS, 2)
void qlin_gemm_i8(const signed char* __restrict__ A, const signed char* __restrict__ B,
                  const float* __restrict__ sx, const int* __restrict__ rowsum,
                  const int* __restrict__ zp,
                  const float* __restrict__ scale, const float* __restrict__ bias,
                  float* __restrict__ C, int M, int N, int K) {
  __shared__ alignas(16) signed char As[2][BM * BK];   // 2 x 16 KiB
  __shared__ alignas(16) signed char Bs[2][BN * BK];   // 2 x 16 KiB

  const int tid  = threadIdx.x;
  const int wave = tid >> 6;
  const int lane = tid & 63;
  const int wm = wave >> 1, wn = wave & 1;       // 2x2 waves; per-wave 64x64

  int bid = blockIdx.x, nwg = gridDim.x, swz = bid;
  if ((nwg & 7) == 0) swz = (bid & 7) * (nwg >> 3) + (bid >> 3);
  const int ntn = N / BN;
  const long row0 = (long)(swz / ntn) * BM;
  const long col0 = (long)(swz % ntn) * BN;

  const signed char* Ag = A + row0 * (long)K;
  const signed char* Bg = B + col0 * (long)K;

  // staging: chunk c = rows [c*32, c*32+32); wave w covers rows c*32+w*8..+8
  // (1 KiB per instr). HW: lane l -> base + l*16 = (row w*8+(l>>3), slot l&7).
  const int srow = wave * 8 + (lane >> 3);              // row within chunk
  const int kswz = ((lane & 7) ^ (lane >> 3)) * 16;     // pre-swizzled bytes

#define STAGE_A(b, c, kt) gload_lds16(Ag + (long)((c)*32 + srow) * K + (kt) + kswz, \
                                      &As[b][(c)*4096 + wave*1024])
#define STAGE_B(b, c, kt) gload_lds16(Bg + (long)((c)*32 + srow) * K + (kt) + kswz, \
                                      &Bs[b][(c)*4096 + wave*1024])
#define STAGE8(b, kt) { STAGE_B(b,0,kt); STAGE_B(b,1,kt); STAGE_B(b,2,kt); STAGE_B(b,3,kt); \
                        STAGE_A(b,0,kt); STAGE_A(b,1,kt); STAGE_A(b,2,kt); STAGE_A(b,3,kt); }

  const int rsel = lane & 15;     // fragment row (within 16)
  const int ksl  = lane >> 4;     // 0..3 -> 16B k-slot within a 64-elem half
  const int lan7 = lane & 7;      // == frag-row & 7 (bases are multiples of 16)

  i32x4 acc[4][4] = {};
  i32x4 bf[4][2];                 // B frags [n][kk], live across one tile

#define AF_READ(bb, m, kk)                                                      \
  (*(const i32x4*)&As[bb][(wm*64 + (m)*16 + rsel)*BK                            \
                          + (((((kk)<<2)+ksl) ^ lan7) << 4)])

#define TILE(bb, STAGES, ENDW)                                                   \
  {                                                                              \
    __builtin_amdgcn_s_setprio(1);                                               \
    _Pragma("unroll")                                                            \
    for (int n = 0; n < 4; ++n)                                                  \
      _Pragma("unroll")                                                          \
      for (int kk = 0; kk < 2; ++kk)                                             \
        bf[n][kk] = *(const i32x4*)&Bs[bb][(wn*64 + n*16 + rsel)*BK              \
                                           + ((((kk<<2)+ksl) ^ lan7) << 4)];     \
    i32x4 afp0, afp1;                                                            \
    afp0 = AF_READ(bb, 0, 0);                                                    \
    _Pragma("unroll")                                                            \
    for (int f = 0; f < 8; ++f) {                                                \
      const int m = f & 3, kk = f >> 2;                                          \
      if (f < 7) {                                                               \
        const int m2 = (f + 1) & 3, kk2 = (f + 1) >> 2;                          \
        if (f & 1) afp0 = AF_READ(bb, m2, kk2);                                  \
        else       afp1 = AF_READ(bb, m2, kk2);                                  \
      }                                                                          \
      _Pragma("unroll")                                                          \
      for (int n = 0; n < 4; ++n)                                                \
        acc[m][n] = __builtin_amdgcn_mfma_i32_16x16x64_i8(                       \
            (f & 1) ? afp1 : afp0, bf[n][kk], acc[m][n], 0, 0, 0);               \
    }                                                                            \
    __builtin_amdgcn_s_setprio(0);                                               \
    tile_barrier();  /* (i) */                                                   \
    STAGES;                                                                      \
    ENDW;                                                                        \
    tile_barrier();  /* (ii) */                                                  \
  }

  const int NT = K / BK;   // 32 for this shape; even, >= 6 (guarded)

  // Prologue: stage tile0 -> buf0, tile1 -> buf1; land tile0 before entering.
  STAGE8(0, 0)
  STAGE8(1, BK)
  vmwait<8>();                       // tile0's 8 retired; tile1's 8 in flight
  tile_barrier();

  // Steady: pairs (t, t+1), literal bufs (0,1); tile t stages t+2.
  for (int t = 0; t < NT - 3; t += 2) {
    const long kt2 = (long)(t + 2) * BK;
    const long kt3 = (long)(t + 3) * BK;
    TILE(0, STAGE8(0, kt2), vmwait<8>())
    TILE(1, STAGE8(1, kt3), vmwait<8>())
  }
  TILE(0, (void)0, vmwait<0>())      // tile NT-2: drain tile NT-1's batch
  TILE(1, (void)0, (void)0)          // tile NT-1: pure compute
#undef TILE
#undef AF_READ
#undef STAGE8
#undef STAGE_A
#undef STAGE_B

  // Epilogue. C/D layout (dtype-independent, m121-128): col = lane&15,
  // row = (lane>>4)*4 + j.  out = sx*sw*(acc - zp*rowsum) + bias.
  float swv[4], bvv[4]; int zpv[4];
  #pragma unroll
  for (int n = 0; n < 4; ++n) {
    const long gcol = col0 + wn * 64 + n * 16 + rsel;
    swv[n] = scale[gcol];
    bvv[n] = bias[gcol];
    zpv[n] = zp[gcol];
  }
  #pragma unroll
  for (int m = 0; m < 4; ++m) {
    const long growb = row0 + wm * 64 + m * 16 + ksl * 4;
    #pragma unroll
    for (int j = 0; j < 4; ++j) {
      const long grow = growb + j;
      const float sxv = sx[grow];
      const int   rsv = rowsum[grow];
      float* orow = C + grow * (long)N;
      #pragma unroll
      for (int n = 0; n < 4; ++n) {
        const long gcol = col0 + wn * 64 + n * 16 + rsel;
        orow[gcol] = (float)(acc[m][n][j] - zpv[n] * rsv) * (sxv * swv[n]) + bvv[n];
      }
    }
  }
}

// ---- fallback (ws too small / odd shape): reg-staged 128x128 bf16, inline dequant ----
__global__ __launch_bounds__(256)
void qlin_gemm_small(const float* __restrict__ Af, const int* __restrict__ Bi,
                     const int* __restrict__ zp,
                     const float* __restrict__ scale, const float* __restrict__ bias,
                     float* __restrict__ C, int M, int N, int K) {
  __shared__ alignas(16) __bf16 As[128 * 64];
  __shared__ alignas(16) __bf16 Bs[128 * 64];
  const int tid = threadIdx.x, wave = tid >> 6, lane = tid & 63;
  int bid = blockIdx.x, nwg = gridDim.x, swz = bid;
  if ((nwg & 7) == 0) swz = (bid & 7) * (nwg >> 3) + (bid >> 3);
  const int ntn = N / 128;
  const long row0 = (long)(swz / ntn) * 128, col0 = (long)(swz % ntn) * 128;
  const int wr = wave >> 1, wc = wave & 1;
  f32x4 acc[4][4] = {};
  for (int kt = 0; kt < K; kt += 64) {
    #pragma unroll
    for (int i = 0; i < 4; ++i) {
      const int flat = i * 2048 + tid * 8;
      const int r = flat >> 6, cc = flat & 63;
      const int wcc = ((cc >> 3) ^ (r & 7)) << 3;
      const float* g = Af + (row0 + r) * (long)K + kt + cc;
      float4 f0 = *(const float4*)g; float4 f1 = *(const float4*)(g + 4);
      bf16x8 v;
      v[0]=(__bf16)f0.x; v[1]=(__bf16)f0.y; v[2]=(__bf16)f0.z; v[3]=(__bf16)f0.w;
      v[4]=(__bf16)f1.x; v[5]=(__bf16)f1.y; v[6]=(__bf16)f1.z; v[7]=(__bf16)f1.w;
      *(bf16x8*)(As + r * 64 + wcc) = v;
    }
    #pragma unroll
    for (int i = 0; i < 4; ++i) {
      const int flat = i * 2048 + tid * 8;
      const int r = flat >> 6, cc = flat & 63;
      const int wcc = ((cc >> 3) ^ (r & 7)) << 3;
      const long grow = col0 + r;
      const int z = zp[grow];
      const int* g = Bi + grow * (long)K + kt + cc;
      int4 a = *(const int4*)g; int4 b = *(const int4*)(g + 4);
      bf16x8 v;
      v[0]=(__bf16)(float)(a.x-z); v[1]=(__bf16)(float)(a.y-z);
      v[2]=(__bf16)(float)(a.z-z); v[3]=(__bf16)(float)(a.w-z);
      v[4]=(__bf16)(float)(b.x-z); v[5]=(__bf16)(float)(b.y-z);
      v[6]=(__bf16)(float)(b.z-z); v[7]=(__bf16)(float)(b.w-z);
      *(bf16x8*)(Bs + r * 64 + wcc) = v;
    }
    __syncthreads();
    #pragma unroll
    for (int kk = 0; kk < 2; ++kk) {
      bf16x8 af[4], bfr[4];
      const int rs = lane & 15, ks = kk * 4 + (lane >> 4);
      const int rd = (ks ^ (lane & 7)) << 3;
      #pragma unroll
      for (int m = 0; m < 4; ++m) af[m] = *(const bf16x8*)(As + (wr*64 + m*16 + rs)*64 + rd);
      #pragma unroll
      for (int n = 0; n < 4; ++n) bfr[n] = *(const bf16x8*)(Bs + (wc*64 + n*16 + rs)*64 + rd);
      #pragma unroll
      for (int m = 0; m < 4; ++m)
        #pragma unroll
        for (int n = 0; n < 4; ++n)
          acc[m][n] = __builtin_amdgcn_mfma_f32_16x16x32_bf16(af[m], bfr[n], acc[m][n], 0, 0, 0);
    }
    __syncthreads();
  }
  #pragma unroll
  for (int m = 0; m < 4; ++m) {
    const long grow = row0 + wr * 64 + m * 16 + ((lane >> 4) << 2);
    #pragma unroll
    for (int n = 0; n < 4; ++n) {
      const long gcol = col0 + wc * 64 + n * 16 + (lane & 15);
      const float s = scale[gcol], bb2 = bias[gcol];
      float* o = C + grow * (long)N + gcol;
      #pragma unroll
      for (int j = 0; j < 4; ++j) o[(long)j * N] = acc[m][n][j] * s + bb2;
    }
  }
}

extern "C" void kernel_launch(void* const* d_in, const int* in_sizes, int n_in,
                              void* d_out, int out_size, void* d_ws, size_t ws_size,
                              hipStream_t stream) {
  const float* x    = (const float*)d_in[0];
  const int*   wint = (const int*)d_in[1];
  const float* wsc  = (const float*)d_in[2];
  const int*   wzp  = (const int*)d_in[3];
  const float* bias = (const float*)d_in[4];
  float* out = (float*)d_out;

  const int N = in_sizes[4];            // 16384 (OUT)
  const int K = in_sizes[1] / N;        // 4096  (IN)
  const int M = in_sizes[0] / K;        // 8192  (B*S)

  const size_t xqb = (size_t)M * K;             // int8 x
  const size_t wqb = (size_t)N * K;             // int8 w
  const size_t sxb = (size_t)M * sizeof(float);
  const size_t rsb = (size_t)M * sizeof(int);
  const int NT = K / BK;

  if (ws_size >= xqb + wqb + sxb + rsb && (M % BM) == 0 && (N % BN) == 0 &&
      (K % BK) == 0 && (K % 4096) == 0 && NT >= 6 && (NT % 2) == 0) {
    signed char* xq = (signed char*)d_ws;
    signed char* wq = xq + xqb;
    float* sx  = (float*)(wq + wqb);
    int* rsum  = (int*)((char*)sx + sxb);
    quant_x<<<M, 256, 0, stream>>>(x, xq, sx, rsum, K);
    conv_w<<<2048, 256, 0, stream>>>(wint, wzp, wq, K, (long)N * K);
    const int grid = (M / BM) * (N / BN); // 64 * 128 = 8192
    qlin_gemm_i8<<<grid, THREADS, 0, stream>>>(xq, wq, sx, rsum, wzp, wsc, bias,
                                               out, M, N, K);
  } else {
    const int grid = (M / 128) * (N / 128);
    qlin_gemm_small<<<grid, 256, 0, stream>>>(x, wint, wzp, wsc, bias, out, M, N, K);
  }
}

// Round 17
// 789.446 us; speedup vs baseline: 5.4240x; 1.0751x over previous
//
#include <hip/hip_runtime.h>
#include <hip/hip_bf16.h>

typedef __bf16 bf16x8 __attribute__((ext_vector_type(8)));
typedef float  f32x4  __attribute__((ext_vector_type(4)));
typedef int    i32x4  __attribute__((ext_vector_type(4)));

#define BM 128
#define BN 128
#define BK 128          // full 128-B rows (r15 lesson)
#define THREADS 256

__device__ __forceinline__ void gload_lds16(const void* g, void* l) {
  __builtin_amdgcn_global_load_lds(
      (const __attribute__((address_space(1))) void*)g,
      (__attribute__((address_space(3))) void*)l, 16, 0, 0);
}

__device__ __forceinline__ void vmwait0() { asm volatile("s_waitcnt vmcnt(0)"); }

__device__ __forceinline__ void tile_barrier() {
  __builtin_amdgcn_sched_barrier(0);
  asm volatile("s_barrier");
  __builtin_amdgcn_sched_barrier(0);
}

// ---- per-row x quantization: sx = rowmax/127, q = rne(x/sx), rowsum = sum q ----
__global__ __launch_bounds__(256)
void quant_x(const float* __restrict__ x, signed char* __restrict__ xq,
             float* __restrict__ sx, int* __restrict__ rowsum, int K) {
  const int row = blockIdx.x, tid = threadIdx.x;
  const int wave = tid >> 6, lane = tid & 63;
  const float* xr = x + (long)row * K;
  __shared__ float smax[4];
  __shared__ int   ssum[4];

  float amax = 0.f;
  for (int i = tid * 16; i < K; i += 256 * 16) {
    #pragma unroll
    for (int j = 0; j < 4; ++j) {
      float4 v = *(const float4*)(xr + i + j * 4);
      amax = fmaxf(amax, fmaxf(fmaxf(fabsf(v.x), fabsf(v.y)),
                               fmaxf(fabsf(v.z), fabsf(v.w))));
    }
  }
  #pragma unroll
  for (int m = 32; m >= 1; m >>= 1) amax = fmaxf(amax, __shfl_xor(amax, m));
  if (lane == 0) smax[wave] = amax;
  __syncthreads();
  const float m4 = fmaxf(fmaxf(smax[0], smax[1]), fmaxf(smax[2], smax[3]));
  const float scale = (m4 > 0.f) ? (m4 / 127.f) : 1.f;
  const float inv   = (m4 > 0.f) ? (127.f / m4) : 0.f;

  int lsum = 0;
  for (int i = tid * 16; i < K; i += 256 * 16) {
    union { signed char c[16]; int4 v; } u;
    #pragma unroll
    for (int j = 0; j < 4; ++j) {
      float4 v = *(const float4*)(xr + i + j * 4);
      int q0 = __float2int_rn(v.x * inv), q1 = __float2int_rn(v.y * inv);
      int q2 = __float2int_rn(v.z * inv), q3 = __float2int_rn(v.w * inv);
      u.c[j*4+0] = (signed char)q0; u.c[j*4+1] = (signed char)q1;
      u.c[j*4+2] = (signed char)q2; u.c[j*4+3] = (signed char)q3;
      lsum += q0 + q1 + q2 + q3;
    }
    *(int4*)(xq + (long)row * K + i) = u.v;
  }
  #pragma unroll
  for (int m = 32; m >= 1; m >>= 1) lsum += __shfl_xor(lsum, m);
  if (lane == 0) ssum[wave] = lsum;
  __syncthreads();
  if (tid == 0) {
    rowsum[row] = ssum[0] + ssum[1] + ssum[2] + ssum[3];
    sx[row] = scale;
  }
}

// ---- (int32 weight - zp) -> int8 (exact for the symmetric-quant data) ----
__global__ void conv_w(const int* __restrict__ w, const int* __restrict__ zp,
                       signed char* __restrict__ wq, int K, long n) {
  long i0 = ((long)blockIdx.x * blockDim.x + threadIdx.x) * 16;
  long stride = (long)gridDim.x * blockDim.x * 16;
  for (long i = i0; i < n; i += stride) {
    const int z = zp[i / K];
    union { signed char c[16]; int4 v; } u;
    #pragma unroll
    for (int j = 0; j < 4; ++j) {
      int4 a = *(const int4*)(w + i + j * 4);
      int q0 = min(127, max(-128, a.x - z)), q1 = min(127, max(-128, a.y - z));
      int q2 = min(127, max(-128, a.z - z)), q3 = min(127, max(-128, a.w - z));
      u.c[j*4+0] = (signed char)q0; u.c[j*4+1] = (signed char)q1;
      u.c[j*4+2] = (signed char)q2; u.c[j*4+3] = (signed char)q3;
    }
    *(int4*)(wq + i) = u.v;
  }
}

// ====== int8 128x128 GEMM, BK=128, SINGLE-buffer 32 KiB -> 3 blocks/CU ======
// Every round so far ran 2 waves/SIMD (r13: 1x512thr block; r16: 2x256thr
// blocks but combined regs 152 -> still 2/SIMD). The m97-proven regime —
// 3 blocks/CU (3 waves/SIMD), single-buffered LDS, plain
// stage -> drain -> barrier -> compute -> barrier — is the one untested
// mechanism: three INDEPENDENT barrier groups per CU give the SIMD scheduler
// a wave to run during any other block's stage/drain (m114/m97 implicit TLP).
// Geometry: 128x128 / 4 waves (2x2) / per-wave 64x64 -> acc[4][4] = 64 AGPR,
// ~70 VGPR -> combined ~134 <= ~170 (3 waves/SIMD cap); LDS single-buffer
// (16+16) KiB -> 3 blocks fit 96 KiB. __launch_bounds__(256,3): min 3
// waves/EU, reg cap well above need (no r14 spill-squeeze).
// Per K-tile (uniform loop, no bufs, no peel):
//   8x gload_lds tile t -> LDS ; vmcnt(0) ; barrier ; [bf x8 ; af-pipelined
//   32 MFMA] ; barrier (WAR for next stage).
// Swizzle (r13/r16 verbatim, verified): LDS[row][slot16B] holds k-slot =
// slot ^ (row&7); stage: wave w rows c*32+w*8+(l>>3), pre-swizzled source
// slot (l&7)^(l>>3); read offset ((kk*4+ksl) ^ (rsel&7))*16.
// Epilogue: out = sx[r]*sw[c]*(acc - zp[c]*rowsum[r]) + bias[c]  (zp exact).
__global__ __launch_bounds__(THREADS, 3)
void qlin_gemm_i8(const signed char* __restrict__ A, const signed char* __restrict__ B,
                  const float* __restrict__ sx, const int* __restrict__ rowsum,
                  const int* __restrict__ zp,
                  const float* __restrict__ scale, const float* __restrict__ bias,
                  float* __restrict__ C, int M, int N, int K) {
  __shared__ alignas(16) signed char As[BM * BK];   // 16 KiB
  __shared__ alignas(16) signed char Bs[BN * BK];   // 16 KiB

  const int tid  = threadIdx.x;
  const int wave = tid >> 6;
  const int lane = tid & 63;
  const int wm = wave >> 1, wn = wave & 1;       // 2x2 waves; per-wave 64x64

  int bid = blockIdx.x, nwg = gridDim.x, swz = bid;
  if ((nwg & 7) == 0) swz = (bid & 7) * (nwg >> 3) + (bid >> 3);
  const int ntn = N / BN;
  const long row0 = (long)(swz / ntn) * BM;
  const long col0 = (long)(swz % ntn) * BN;

  const signed char* Ag = A + row0 * (long)K;
  const signed char* Bg = B + col0 * (long)K;

  // staging: chunk c = rows [c*32, c*32+32); wave w covers rows c*32+w*8..+8
  // (1 KiB per instr). HW: lane l -> base + l*16 = (row w*8+(l>>3), slot l&7).
  const int srow = wave * 8 + (lane >> 3);              // row within chunk
  const int kswz = ((lane & 7) ^ (lane >> 3)) * 16;     // pre-swizzled bytes

#define STAGE_A(c, kt) gload_lds16(Ag + (long)((c)*32 + srow) * K + (kt) + kswz, \
                                   &As[(c)*4096 + wave*1024])
#define STAGE_B(c, kt) gload_lds16(Bg + (long)((c)*32 + srow) * K + (kt) + kswz, \
                                   &Bs[(c)*4096 + wave*1024])
#define STAGE8(kt) { STAGE_B(0,kt); STAGE_B(1,kt); STAGE_B(2,kt); STAGE_B(3,kt); \
                     STAGE_A(0,kt); STAGE_A(1,kt); STAGE_A(2,kt); STAGE_A(3,kt); }

  const int rsel = lane & 15;     // fragment row (within 16)
  const int ksl  = lane >> 4;     // 0..3 -> 16B k-slot within a 64-elem half
  const int lan7 = lane & 7;      // == frag-row & 7 (bases are multiples of 16)

  i32x4 acc[4][4] = {};
  i32x4 bf[4][2];                 // B frags [n][kk]

#define AF_READ(m, kk)                                                          \
  (*(const i32x4*)&As[(wm*64 + (m)*16 + rsel)*BK                                \
                      + (((((kk)<<2)+ksl) ^ lan7) << 4)])

  const int NT = K / BK;   // 32 for this shape

  for (int t = 0; t < NT; ++t) {
    const long kt = (long)t * BK;
    STAGE8(kt)
    vmwait0();
    tile_barrier();          // all waves' stages landed

    __builtin_amdgcn_s_setprio(1);
    #pragma unroll
    for (int n = 0; n < 4; ++n)
      #pragma unroll
      for (int kk = 0; kk < 2; ++kk)
        bf[n][kk] = *(const i32x4*)&Bs[(wn*64 + n*16 + rsel)*BK
                                       + ((((kk<<2)+ksl) ^ lan7) << 4)];
    i32x4 afp0, afp1;
    afp0 = AF_READ(0, 0);
    #pragma unroll
    for (int f = 0; f < 8; ++f) {
      const int m = f & 3, kk = f >> 2;
      if (f < 7) {
        const int m2 = (f + 1) & 3, kk2 = (f + 1) >> 2;
        if (f & 1) afp0 = AF_READ(m2, kk2);
        else       afp1 = AF_READ(m2, kk2);
      }
      #pragma unroll
      for (int n = 0; n < 4; ++n)
        acc[m][n] = __builtin_amdgcn_mfma_i32_16x16x64_i8(
            (f & 1) ? afp1 : afp0, bf[n][kk], acc[m][n], 0, 0, 0);
    }
    __builtin_amdgcn_s_setprio(0);
    tile_barrier();          // WAR: reads done before next stage overwrites
  }
#undef AF_READ
#undef STAGE8
#undef STAGE_A
#undef STAGE_B

  // Epilogue. C/D layout (dtype-independent, m121-128): col = lane&15,
  // row = (lane>>4)*4 + j.  out = sx*sw*(acc - zp*rowsum) + bias.
  float swv[4], bvv[4]; int zpv[4];
  #pragma unroll
  for (int n = 0; n < 4; ++n) {
    const long gcol = col0 + wn * 64 + n * 16 + rsel;
    swv[n] = scale[gcol];
    bvv[n] = bias[gcol];
    zpv[n] = zp[gcol];
  }
  #pragma unroll
  for (int m = 0; m < 4; ++m) {
    const long growb = row0 + wm * 64 + m * 16 + ksl * 4;
    #pragma unroll
    for (int j = 0; j < 4; ++j) {
      const long grow = growb + j;
      const float sxv = sx[grow];
      const int   rsv = rowsum[grow];
      float* orow = C + grow * (long)N;
      #pragma unroll
      for (int n = 0; n < 4; ++n) {
        const long gcol = col0 + wn * 64 + n * 16 + rsel;
        orow[gcol] = (float)(acc[m][n][j] - zpv[n] * rsv) * (sxv * swv[n]) + bvv[n];
      }
    }
  }
}

// ---- fallback (ws too small / odd shape): reg-staged 128x128 bf16, inline dequant ----
__global__ __launch_bounds__(256)
void qlin_gemm_small(const float* __restrict__ Af, const int* __restrict__ Bi,
                     const int* __restrict__ zp,
                     const float* __restrict__ scale, const float* __restrict__ bias,
                     float* __restrict__ C, int M, int N, int K) {
  __shared__ alignas(16) __bf16 As[128 * 64];
  __shared__ alignas(16) __bf16 Bs[128 * 64];
  const int tid = threadIdx.x, wave = tid >> 6, lane = tid & 63;
  int bid = blockIdx.x, nwg = gridDim.x, swz = bid;
  if ((nwg & 7) == 0) swz = (bid & 7) * (nwg >> 3) + (bid >> 3);
  const int ntn = N / 128;
  const long row0 = (long)(swz / ntn) * 128, col0 = (long)(swz % ntn) * 128;
  const int wr = wave >> 1, wc = wave & 1;
  f32x4 acc[4][4] = {};
  for (int kt = 0; kt < K; kt += 64) {
    #pragma unroll
    for (int i = 0; i < 4; ++i) {
      const int flat = i * 2048 + tid * 8;
      const int r = flat >> 6, cc = flat & 63;
      const int wcc = ((cc >> 3) ^ (r & 7)) << 3;
      const float* g = Af + (row0 + r) * (long)K + kt + cc;
      float4 f0 = *(const float4*)g; float4 f1 = *(const float4*)(g + 4);
      bf16x8 v;
      v[0]=(__bf16)f0.x; v[1]=(__bf16)f0.y; v[2]=(__bf16)f0.z; v[3]=(__bf16)f0.w;
      v[4]=(__bf16)f1.x; v[5]=(__bf16)f1.y; v[6]=(__bf16)f1.z; v[7]=(__bf16)f1.w;
      *(bf16x8*)(As + r * 64 + wcc) = v;
    }
    #pragma unroll
    for (int i = 0; i < 4; ++i) {
      const int flat = i * 2048 + tid * 8;
      const int r = flat >> 6, cc = flat & 63;
      const int wcc = ((cc >> 3) ^ (r & 7)) << 3;
      const long grow = col0 + r;
      const int z = zp[grow];
      const int* g = Bi + grow * (long)K + kt + cc;
      int4 a = *(const int4*)g; int4 b = *(const int4*)(g + 4);
      bf16x8 v;
      v[0]=(__bf16)(float)(a.x-z); v[1]=(__bf16)(float)(a.y-z);
      v[2]=(__bf16)(float)(a.z-z); v[3]=(__bf16)(float)(a.w-z);
      v[4]=(__bf16)(float)(b.x-z); v[5]=(__bf16)(float)(b.y-z);
      v[6]=(__bf16)(float)(b.z-z); v[7]=(__bf16)(float)(b.w-z);
      *(bf16x8*)(Bs + r * 64 + wcc) = v;
    }
    __syncthreads();
    #pragma unroll
    for (int kk = 0; kk < 2; ++kk) {
      bf16x8 af[4], bfr[4];
      const int rs = lane & 15, ks = kk * 4 + (lane >> 4);
      const int rd = (ks ^ (lane & 7)) << 3;
      #pragma unroll
      for (int m = 0; m < 4; ++m) af[m] = *(const bf16x8*)(As + (wr*64 + m*16 + rs)*64 + rd);
      #pragma unroll
      for (int n = 0; n < 4; ++n) bfr[n] = *(const bf16x8*)(Bs + (wc*64 + n*16 + rs)*64 + rd);
      #pragma unroll
      for (int m = 0; m < 4; ++m)
        #pragma unroll
        for (int n = 0; n < 4; ++n)
          acc[m][n] = __builtin_amdgcn_mfma_f32_16x16x32_bf16(af[m], bfr[n], acc[m][n], 0, 0, 0);
    }
    __syncthreads();
  }
  #pragma unroll
  for (int m = 0; m < 4; ++m) {
    const long grow = row0 + wr * 64 + m * 16 + ((lane >> 4) << 2);
    #pragma unroll
    for (int n = 0; n < 4; ++n) {
      const long gcol = col0 + wc * 64 + n * 16 + (lane & 15);
      const float s = scale[gcol], bb2 = bias[gcol];
      float* o = C + grow * (long)N + gcol;
      #pragma unroll
      for (int j = 0; j < 4; ++j) o[(long)j * N] = acc[m][n][j] * s + bb2;
    }
  }
}

extern "C" void kernel_launch(void* const* d_in, const int* in_sizes, int n_in,
                              void* d_out, int out_size, void* d_ws, size_t ws_size,
                              hipStream_t stream) {
  const float* x    = (const float*)d_in[0];
  const int*   wint = (const int*)d_in[1];
  const float* wsc  = (const float*)d_in[2];
  const int*   wzp  = (const int*)d_in[3];
  const float* bias = (const float*)d_in[4];
  float* out = (float*)d_out;

  const int N = in_sizes[4];            // 16384 (OUT)
  const int K = in_sizes[1] / N;        // 4096  (IN)
  const int M = in_sizes[0] / K;        // 8192  (B*S)

  const size_t xqb = (size_t)M * K;             // int8 x
  const size_t wqb = (size_t)N * K;             // int8 w
  const size_t sxb = (size_t)M * sizeof(float);
  const size_t rsb = (size_t)M * sizeof(int);
  const int NT = K / BK;

  if (ws_size >= xqb + wqb + sxb + rsb && (M % BM) == 0 && (N % BN) == 0 &&
      (K % BK) == 0 && (K % 4096) == 0 && NT >= 2) {
    signed char* xq = (signed char*)d_ws;
    signed char* wq = xq + xqb;
    float* sx  = (float*)(wq + wqb);
    int* rsum  = (int*)((char*)sx + sxb);
    quant_x<<<M, 256, 0, stream>>>(x, xq, sx, rsum, K);
    conv_w<<<2048, 256, 0, stream>>>(wint, wzp, wq, K, (long)N * K);
    const int grid = (M / BM) * (N / BN); // 64 * 128 = 8192
    qlin_gemm_i8<<<grid, THREADS, 0, stream>>>(xq, wq, sx, rsum, wzp, wsc, bias,
                                               out, M, N, K);
  } else {
    const int grid = (M / 128) * (N / 128);
    qlin_gemm_small<<<grid, 256, 0, stream>>>(x, wint, wzp, wsc, bias, out, M, N, K);
  }
}

// Round 18
// 700.348 us; speedup vs baseline: 6.1140x; 1.1272x over previous
//
#include <hip/hip_runtime.h>
#include <hip/hip_bf16.h>

typedef __bf16 bf16x8 __attribute__((ext_vector_type(8)));
typedef float  f32x4  __attribute__((ext_vector_type(4)));
typedef int    i32x4  __attribute__((ext_vector_type(4)));

#define BM 128
#define BN 128
#define BK 128          // full 128-B rows (r15 lesson)
#define THREADS 256

__device__ __forceinline__ void gload_lds16(const void* g, void* l) {
  __builtin_amdgcn_global_load_lds(
      (const __attribute__((address_space(1))) void*)g,
      (__attribute__((address_space(3))) void*)l, 16, 0, 0);
}

__device__ __forceinline__ void vmwait0() { asm volatile("s_waitcnt vmcnt(0)"); }

__device__ __forceinline__ void tile_barrier() {
  __builtin_amdgcn_sched_barrier(0);
  asm volatile("s_barrier");
  __builtin_amdgcn_sched_barrier(0);
}

// ---- per-row x quantization: sx = rowmax/127, q = rne(x/sx), rowsum = sum q ----
__global__ __launch_bounds__(256)
void quant_x(const float* __restrict__ x, signed char* __restrict__ xq,
             float* __restrict__ sx, int* __restrict__ rowsum, int K) {
  const int row = blockIdx.x, tid = threadIdx.x;
  const int wave = tid >> 6, lane = tid & 63;
  const float* xr = x + (long)row * K;
  __shared__ float smax[4];
  __shared__ int   ssum[4];

  float amax = 0.f;
  for (int i = tid * 16; i < K; i += 256 * 16) {
    #pragma unroll
    for (int j = 0; j < 4; ++j) {
      float4 v = *(const float4*)(xr + i + j * 4);
      amax = fmaxf(amax, fmaxf(fmaxf(fabsf(v.x), fabsf(v.y)),
                               fmaxf(fabsf(v.z), fabsf(v.w))));
    }
  }
  #pragma unroll
  for (int m = 32; m >= 1; m >>= 1) amax = fmaxf(amax, __shfl_xor(amax, m));
  if (lane == 0) smax[wave] = amax;
  __syncthreads();
  const float m4 = fmaxf(fmaxf(smax[0], smax[1]), fmaxf(smax[2], smax[3]));
  const float scale = (m4 > 0.f) ? (m4 / 127.f) : 1.f;
  const float inv   = (m4 > 0.f) ? (127.f / m4) : 0.f;

  int lsum = 0;
  for (int i = tid * 16; i < K; i += 256 * 16) {
    union { signed char c[16]; int4 v; } u;
    #pragma unroll
    for (int j = 0; j < 4; ++j) {
      float4 v = *(const float4*)(xr + i + j * 4);
      int q0 = __float2int_rn(v.x * inv), q1 = __float2int_rn(v.y * inv);
      int q2 = __float2int_rn(v.z * inv), q3 = __float2int_rn(v.w * inv);
      u.c[j*4+0] = (signed char)q0; u.c[j*4+1] = (signed char)q1;
      u.c[j*4+2] = (signed char)q2; u.c[j*4+3] = (signed char)q3;
      lsum += q0 + q1 + q2 + q3;
    }
    *(int4*)(xq + (long)row * K + i) = u.v;
  }
  #pragma unroll
  for (int m = 32; m >= 1; m >>= 1) lsum += __shfl_xor(lsum, m);
  if (lane == 0) ssum[wave] = lsum;
  __syncthreads();
  if (tid == 0) {
    rowsum[row] = ssum[0] + ssum[1] + ssum[2] + ssum[3];
    sx[row] = scale;
  }
}

// ---- (int32 weight - zp) -> int8 (exact for the symmetric-quant data) ----
__global__ void conv_w(const int* __restrict__ w, const int* __restrict__ zp,
                       signed char* __restrict__ wq, int K, long n) {
  long i0 = ((long)blockIdx.x * blockDim.x + threadIdx.x) * 16;
  long stride = (long)gridDim.x * blockDim.x * 16;
  for (long i = i0; i < n; i += stride) {
    const int z = zp[i / K];
    union { signed char c[16]; int4 v; } u;
    #pragma unroll
    for (int j = 0; j < 4; ++j) {
      int4 a = *(const int4*)(w + i + j * 4);
      int q0 = min(127, max(-128, a.x - z)), q1 = min(127, max(-128, a.y - z));
      int q2 = min(127, max(-128, a.z - z)), q3 = min(127, max(-128, a.w - z));
      u.c[j*4+0] = (signed char)q0; u.c[j*4+1] = (signed char)q1;
      u.c[j*4+2] = (signed char)q2; u.c[j*4+3] = (signed char)q3;
    }
    *(int4*)(wq + i) = u.v;
  }
}

// ====== int8 128x128 GEMM, BK=128, single-buffer, 3-4 blocks/CU ======
// r17 established the working regime: single-buffer 32 KiB LDS, 3-4
// independent barrier groups/CU, occupancy 45%, duration == hbm_bytes/3.9TB/s
// (cleanly FETCH-bound; MfmaUtil 31% = starvation). This round changes ONLY
// the block-index mapping: within each XCD's 8-row stripe, blocks were
// row-major -> ~112 concurrent blocks stream 112 distinct B col-panels
// (56 MB >> 4 MB L2) -> B refetched every row sweep (FETCH 2.17 GB).
// New mapping: 8x8 PATCHES within the stripe -> concurrent blocks share
// 8 row-panels + ~8-16 col-panels (~4-8 MB working set) -> each B panel
// serves 8 blocks from L2. Bijective: l = patch*64 + (c%8)*8 + r over the
// stripe; guarded by nwg%8==0 && ntm%8==0 && ntn%8==0 (else old swizzle).
// Kernel body (stage/swizzle/compute/epilogue) is r17 VERBATIM.
__global__ __launch_bounds__(THREADS, 3)
void qlin_gemm_i8(const signed char* __restrict__ A, const signed char* __restrict__ B,
                  const float* __restrict__ sx, const int* __restrict__ rowsum,
                  const int* __restrict__ zp,
                  const float* __restrict__ scale, const float* __restrict__ bias,
                  float* __restrict__ C, int M, int N, int K) {
  __shared__ alignas(16) signed char As[BM * BK];   // 16 KiB
  __shared__ alignas(16) signed char Bs[BN * BK];   // 16 KiB

  const int tid  = threadIdx.x;
  const int wave = tid >> 6;
  const int lane = tid & 63;
  const int wm = wave >> 1, wn = wave & 1;       // 2x2 waves; per-wave 64x64

  const int bid = blockIdx.x, nwg = gridDim.x;
  const int ntn = N / BN, ntm = M / BM;
  long tm, tn;
  if ((nwg & 7) == 0 && (ntm & 7) == 0 && (ntn & 7) == 0 &&
      (nwg >> 3) == (ntm >> 3) * ntn) {
    // XCD-chunked stripe (R=ntm/8 rows x ntn cols) + 8-col patches.
    const int xcd = bid & 7;
    const int l   = bid >> 3;            // local index within stripe
    const int R   = ntm >> 3;            // stripe rows
    const int ps  = R << 3;              // patch size = R*8 blocks
    const int w   = l % ps;
    tm = (long)xcd * R + (w % R);
    tn = (long)(l / ps) * 8 + (w / R);
  } else {
    tm = bid / ntn; tn = bid % ntn;
  }
  const long row0 = tm * BM;
  const long col0 = tn * BN;

  const signed char* Ag = A + row0 * (long)K;
  const signed char* Bg = B + col0 * (long)K;

  // staging: chunk c = rows [c*32, c*32+32); wave w covers rows c*32+w*8..+8
  // (1 KiB per instr). HW: lane l -> base + l*16 = (row w*8+(l>>3), slot l&7).
  const int srow = wave * 8 + (lane >> 3);              // row within chunk
  const int kswz = ((lane & 7) ^ (lane >> 3)) * 16;     // pre-swizzled bytes

#define STAGE_A(c, kt) gload_lds16(Ag + (long)((c)*32 + srow) * K + (kt) + kswz, \
                                   &As[(c)*4096 + wave*1024])
#define STAGE_B(c, kt) gload_lds16(Bg + (long)((c)*32 + srow) * K + (kt) + kswz, \
                                   &Bs[(c)*4096 + wave*1024])
#define STAGE8(kt) { STAGE_B(0,kt); STAGE_B(1,kt); STAGE_B(2,kt); STAGE_B(3,kt); \
                     STAGE_A(0,kt); STAGE_A(1,kt); STAGE_A(2,kt); STAGE_A(3,kt); }

  const int rsel = lane & 15;     // fragment row (within 16)
  const int ksl  = lane >> 4;     // 0..3 -> 16B k-slot within a 64-elem half
  const int lan7 = lane & 7;      // == frag-row & 7 (bases are multiples of 16)

  i32x4 acc[4][4] = {};
  i32x4 bf[4][2];                 // B frags [n][kk]

#define AF_READ(m, kk)                                                          \
  (*(const i32x4*)&As[(wm*64 + (m)*16 + rsel)*BK                                \
                      + (((((kk)<<2)+ksl) ^ lan7) << 4)])

  const int NT = K / BK;   // 32 for this shape

  for (int t = 0; t < NT; ++t) {
    const long kt = (long)t * BK;
    STAGE8(kt)
    vmwait0();
    tile_barrier();          // all waves' stages landed

    __builtin_amdgcn_s_setprio(1);
    #pragma unroll
    for (int n = 0; n < 4; ++n)
      #pragma unroll
      for (int kk = 0; kk < 2; ++kk)
        bf[n][kk] = *(const i32x4*)&Bs[(wn*64 + n*16 + rsel)*BK
                                       + ((((kk<<2)+ksl) ^ lan7) << 4)];
    i32x4 afp0, afp1;
    afp0 = AF_READ(0, 0);
    #pragma unroll
    for (int f = 0; f < 8; ++f) {
      const int m = f & 3, kk = f >> 2;
      if (f < 7) {
        const int m2 = (f + 1) & 3, kk2 = (f + 1) >> 2;
        if (f & 1) afp0 = AF_READ(m2, kk2);
        else       afp1 = AF_READ(m2, kk2);
      }
      #pragma unroll
      for (int n = 0; n < 4; ++n)
        acc[m][n] = __builtin_amdgcn_mfma_i32_16x16x64_i8(
            (f & 1) ? afp1 : afp0, bf[n][kk], acc[m][n], 0, 0, 0);
    }
    __builtin_amdgcn_s_setprio(0);
    tile_barrier();          // WAR: reads done before next stage overwrites
  }
#undef AF_READ
#undef STAGE8
#undef STAGE_A
#undef STAGE_B

  // Epilogue. C/D layout (dtype-independent, m121-128): col = lane&15,
  // row = (lane>>4)*4 + j.  out = sx*sw*(acc - zp*rowsum) + bias.
  float swv[4], bvv[4]; int zpv[4];
  #pragma unroll
  for (int n = 0; n < 4; ++n) {
    const long gcol = col0 + wn * 64 + n * 16 + rsel;
    swv[n] = scale[gcol];
    bvv[n] = bias[gcol];
    zpv[n] = zp[gcol];
  }
  #pragma unroll
  for (int m = 0; m < 4; ++m) {
    const long growb = row0 + wm * 64 + m * 16 + ksl * 4;
    #pragma unroll
    for (int j = 0; j < 4; ++j) {
      const long grow = growb + j;
      const float sxv = sx[grow];
      const int   rsv = rowsum[grow];
      float* orow = C + grow * (long)N;
      #pragma unroll
      for (int n = 0; n < 4; ++n) {
        const long gcol = col0 + wn * 64 + n * 16 + rsel;
        orow[gcol] = (float)(acc[m][n][j] - zpv[n] * rsv) * (sxv * swv[n]) + bvv[n];
      }
    }
  }
}

// ---- fallback (ws too small / odd shape): reg-staged 128x128 bf16, inline dequant ----
__global__ __launch_bounds__(256)
void qlin_gemm_small(const float* __restrict__ Af, const int* __restrict__ Bi,
                     const int* __restrict__ zp,
                     const float* __restrict__ scale, const float* __restrict__ bias,
                     float* __restrict__ C, int M, int N, int K) {
  __shared__ alignas(16) __bf16 As[128 * 64];
  __shared__ alignas(16) __bf16 Bs[128 * 64];
  const int tid = threadIdx.x, wave = tid >> 6, lane = tid & 63;
  int bid = blockIdx.x, nwg = gridDim.x, swz = bid;
  if ((nwg & 7) == 0) swz = (bid & 7) * (nwg >> 3) + (bid >> 3);
  const int ntn = N / 128;
  const long row0 = (long)(swz / ntn) * 128, col0 = (long)(swz % ntn) * 128;
  const int wr = wave >> 1, wc = wave & 1;
  f32x4 acc[4][4] = {};
  for (int kt = 0; kt < K; kt += 64) {
    #pragma unroll
    for (int i = 0; i < 4; ++i) {
      const int flat = i * 2048 + tid * 8;
      const int r = flat >> 6, cc = flat & 63;
      const int wcc = ((cc >> 3) ^ (r & 7)) << 3;
      const float* g = Af + (row0 + r) * (long)K + kt + cc;
      float4 f0 = *(const float4*)g; float4 f1 = *(const float4*)(g + 4);
      bf16x8 v;
      v[0]=(__bf16)f0.x; v[1]=(__bf16)f0.y; v[2]=(__bf16)f0.z; v[3]=(__bf16)f0.w;
      v[4]=(__bf16)f1.x; v[5]=(__bf16)f1.y; v[6]=(__bf16)f1.z; v[7]=(__bf16)f1.w;
      *(bf16x8*)(As + r * 64 + wcc) = v;
    }
    #pragma unroll
    for (int i = 0; i < 4; ++i) {
      const int flat = i * 2048 + tid * 8;
      const int r = flat >> 6, cc = flat & 63;
      const int wcc = ((cc >> 3) ^ (r & 7)) << 3;
      const long grow = col0 + r;
      const int z = zp[grow];
      const int* g = Bi + grow * (long)K + kt + cc;
      int4 a = *(const int4*)g; int4 b = *(const int4*)(g + 4);
      bf16x8 v;
      v[0]=(__bf16)(float)(a.x-z); v[1]=(__bf16)(float)(a.y-z);
      v[2]=(__bf16)(float)(a.z-z); v[3]=(__bf16)(float)(a.w-z);
      v[4]=(__bf16)(float)(b.x-z); v[5]=(__bf16)(float)(b.y-z);
      v[6]=(__bf16)(float)(b.z-z); v[7]=(__bf16)(float)(b.w-z);
      *(bf16x8*)(Bs + r * 64 + wcc) = v;
    }
    __syncthreads();
    #pragma unroll
    for (int kk = 0; kk < 2; ++kk) {
      bf16x8 af[4], bfr[4];
      const int rs = lane & 15, ks = kk * 4 + (lane >> 4);
      const int rd = (ks ^ (lane & 7)) << 3;
      #pragma unroll
      for (int m = 0; m < 4; ++m) af[m] = *(const bf16x8*)(As + (wr*64 + m*16 + rs)*64 + rd);
      #pragma unroll
      for (int n = 0; n < 4; ++n) bfr[n] = *(const bf16x8*)(Bs + (wc*64 + n*16 + rs)*64 + rd);
      #pragma unroll
      for (int m = 0; m < 4; ++m)
        #pragma unroll
        for (int n = 0; n < 4; ++n)
          acc[m][n] = __builtin_amdgcn_mfma_f32_16x16x32_bf16(af[m], bfr[n], acc[m][n], 0, 0, 0);
    }
    __syncthreads();
  }
  #pragma unroll
  for (int m = 0; m < 4; ++m) {
    const long grow = row0 + wr * 64 + m * 16 + ((lane >> 4) << 2);
    #pragma unroll
    for (int n = 0; n < 4; ++n) {
      const long gcol = col0 + wc * 64 + n * 16 + (lane & 15);
      const float s = scale[gcol], bb2 = bias[gcol];
      float* o = C + grow * (long)N + gcol;
      #pragma unroll
      for (int j = 0; j < 4; ++j) o[(long)j * N] = acc[m][n][j] * s + bb2;
    }
  }
}

extern "C" void kernel_launch(void* const* d_in, const int* in_sizes, int n_in,
                              void* d_out, int out_size, void* d_ws, size_t ws_size,
                              hipStream_t stream) {
  const float* x    = (const float*)d_in[0];
  const int*   wint = (const int*)d_in[1];
  const float* wsc  = (const float*)d_in[2];
  const int*   wzp  = (const int*)d_in[3];
  const float* bias = (const float*)d_in[4];
  float* out = (float*)d_out;

  const int N = in_sizes[4];            // 16384 (OUT)
  const int K = in_sizes[1] / N;        // 4096  (IN)
  const int M = in_sizes[0] / K;        // 8192  (B*S)

  const size_t xqb = (size_t)M * K;             // int8 x
  const size_t wqb = (size_t)N * K;             // int8 w
  const size_t sxb = (size_t)M * sizeof(float);
  const size_t rsb = (size_t)M * sizeof(int);
  const int NT = K / BK;

  if (ws_size >= xqb + wqb + sxb + rsb && (M % BM) == 0 && (N % BN) == 0 &&
      (K % BK) == 0 && (K % 4096) == 0 && NT >= 2) {
    signed char* xq = (signed char*)d_ws;
    signed char* wq = xq + xqb;
    float* sx  = (float*)(wq + wqb);
    int* rsum  = (int*)((char*)sx + sxb);
    quant_x<<<M, 256, 0, stream>>>(x, xq, sx, rsum, K);
    conv_w<<<2048, 256, 0, stream>>>(wint, wzp, wq, K, (long)N * K);
    const int grid = (M / BM) * (N / BN); // 64 * 128 = 8192
    qlin_gemm_i8<<<grid, THREADS, 0, stream>>>(xq, wq, sx, rsum, wzp, wsc, bias,
                                               out, M, N, K);
  } else {
    const int grid = (M / 128) * (N / 128);
    qlin_gemm_small<<<grid, 256, 0, stream>>>(x, wint, wzp, wsc, bias, out, M, N, K);
  }
}

// Round 19
// 692.186 us; speedup vs baseline: 6.1861x; 1.0118x over previous
//
#include <hip/hip_runtime.h>
#include <hip/hip_bf16.h>

typedef __bf16 bf16x8 __attribute__((ext_vector_type(8)));
typedef float  f32x4  __attribute__((ext_vector_type(4)));
typedef int    i32x4  __attribute__((ext_vector_type(4)));

#define BM 128
#define BN 128
#define BK 128          // full 128-B rows (r15 lesson)
#define THREADS 256

__device__ __forceinline__ void gload_lds16(const void* g, void* l) {
  __builtin_amdgcn_global_load_lds(
      (const __attribute__((address_space(1))) void*)g,
      (__attribute__((address_space(3))) void*)l, 16, 0, 0);
}

__device__ __forceinline__ void vmwait0() { asm volatile("s_waitcnt vmcnt(0)"); }

__device__ __forceinline__ void tile_barrier() {
  __builtin_amdgcn_sched_barrier(0);
  asm volatile("s_barrier");
  __builtin_amdgcn_sched_barrier(0);
}

// ---- FUSED prep: blocks [0,M) quantize x rows; blocks [M, M+NK/4096) convert W.
// The two jobs are independent and memory-bound; one dispatch runs them
// concurrently (sequential launches serialized ~105 us -> ~90 us combined).
// quant: sx = rowmax/127, q = rne(x/sx), rowsum = sum q (for exact zp term).
// conv:  wq = clamp(w - zp, -128, 127)  (exact for the symmetric-quant data).
__global__ __launch_bounds__(256)
void prep_kernel(const float* __restrict__ x, signed char* __restrict__ xq,
                 float* __restrict__ sx, int* __restrict__ rowsum,
                 const int* __restrict__ w, const int* __restrict__ zp,
                 signed char* __restrict__ wq, int M, int K) {
  const int tid = threadIdx.x;
  if ((int)blockIdx.x < M) {
    // ---- x-row quantization (one block per row) ----
    const int row = blockIdx.x;
    const int wave = tid >> 6, lane = tid & 63;
    const float* xr = x + (long)row * K;
    __shared__ float smax[4];
    __shared__ int   ssum[4];

    float amax = 0.f;
    for (int i = tid * 16; i < K; i += 256 * 16) {
      #pragma unroll
      for (int j = 0; j < 4; ++j) {
        float4 v = *(const float4*)(xr + i + j * 4);
        amax = fmaxf(amax, fmaxf(fmaxf(fabsf(v.x), fabsf(v.y)),
                                 fmaxf(fabsf(v.z), fabsf(v.w))));
      }
    }
    #pragma unroll
    for (int m = 32; m >= 1; m >>= 1) amax = fmaxf(amax, __shfl_xor(amax, m));
    if (lane == 0) smax[wave] = amax;
    __syncthreads();
    const float m4 = fmaxf(fmaxf(smax[0], smax[1]), fmaxf(smax[2], smax[3]));
    const float scale = (m4 > 0.f) ? (m4 / 127.f) : 1.f;
    const float inv   = (m4 > 0.f) ? (127.f / m4) : 0.f;

    int lsum = 0;
    for (int i = tid * 16; i < K; i += 256 * 16) {
      union { signed char c[16]; int4 v; } u;
      #pragma unroll
      for (int j = 0; j < 4; ++j) {
        float4 v = *(const float4*)(xr + i + j * 4);
        int q0 = __float2int_rn(v.x * inv), q1 = __float2int_rn(v.y * inv);
        int q2 = __float2int_rn(v.z * inv), q3 = __float2int_rn(v.w * inv);
        u.c[j*4+0] = (signed char)q0; u.c[j*4+1] = (signed char)q1;
        u.c[j*4+2] = (signed char)q2; u.c[j*4+3] = (signed char)q3;
        lsum += q0 + q1 + q2 + q3;
      }
      *(int4*)(xq + (long)row * K + i) = u.v;
    }
    #pragma unroll
    for (int m = 32; m >= 1; m >>= 1) lsum += __shfl_xor(lsum, m);
    if (lane == 0) ssum[wave] = lsum;
    __syncthreads();
    if (tid == 0) {
      rowsum[row] = ssum[0] + ssum[1] + ssum[2] + ssum[3];
      sx[row] = scale;
    }
  } else {
    // ---- weight conversion: 4096 contiguous elems per block ----
    const long i = ((long)(blockIdx.x - M) * 4096) + tid * 16;
    const int z = zp[i / K];   // 16-elem chunk never crosses a row (K%16==0)
    union { signed char c[16]; int4 v; } u;
    #pragma unroll
    for (int j = 0; j < 4; ++j) {
      int4 a = *(const int4*)(w + i + j * 4);
      int q0 = min(127, max(-128, a.x - z)), q1 = min(127, max(-128, a.y - z));
      int q2 = min(127, max(-128, a.z - z)), q3 = min(127, max(-128, a.w - z));
      u.c[j*4+0] = (signed char)q0; u.c[j*4+1] = (signed char)q1;
      u.c[j*4+2] = (signed char)q2; u.c[j*4+3] = (signed char)q3;
    }
    *(int4*)(wq + i) = u.v;
  }
}

// ====== int8 128x128 GEMM, BK=128, single-buffer, ~4 blocks/CU ======
// r18-verbatim (best measured: 573 us, MfmaUtil 49%, FETCH 0.75 GB,
// conflicts 0). Regime: single-buffer 32 KiB LDS + 128 combined regs
// (64 VGPR + 64 AGPR) -> 4 independent barrier groups/CU provide the
// overlap (m114 TLP); XCD-stripe + 8x8-patch block mapping keeps the
// concurrent working set (~4-8 MB) L2-resident (FETCH 2.17 -> 0.75 GB).
// Ledger at 573 us: MFMA floor 278 us (49%), LDS 73 B/cy (28% of peak),
// HBM 2.3 TB/s (36%) -> latency/sync-bound on the per-tile serial chain;
// all deeper-pipeline alternatives trade away the 4-group TLP (r14/r16)
// or are compiler-null (r7-r13). This is the structure's plateau.
__global__ __launch_bounds__(THREADS, 3)
void qlin_gemm_i8(const signed char* __restrict__ A, const signed char* __restrict__ B,
                  const float* __restrict__ sx, const int* __restrict__ rowsum,
                  const int* __restrict__ zp,
                  const float* __restrict__ scale, const float* __restrict__ bias,
                  float* __restrict__ C, int M, int N, int K) {
  __shared__ alignas(16) signed char As[BM * BK];   // 16 KiB
  __shared__ alignas(16) signed char Bs[BN * BK];   // 16 KiB

  const int tid  = threadIdx.x;
  const int wave = tid >> 6;
  const int lane = tid & 63;
  const int wm = wave >> 1, wn = wave & 1;       // 2x2 waves; per-wave 64x64

  const int bid = blockIdx.x, nwg = gridDim.x;
  const int ntn = N / BN, ntm = M / BM;
  long tm, tn;
  if ((nwg & 7) == 0 && (ntm & 7) == 0 && (ntn & 7) == 0 &&
      (nwg >> 3) == (ntm >> 3) * ntn) {
    // XCD-chunked stripe (R=ntm/8 rows x ntn cols) + 8-col patches.
    const int xcd = bid & 7;
    const int l   = bid >> 3;            // local index within stripe
    const int R   = ntm >> 3;            // stripe rows
    const int ps  = R << 3;              // patch size = R*8 blocks
    const int w   = l % ps;
    tm = (long)xcd * R + (w % R);
    tn = (long)(l / ps) * 8 + (w / R);
  } else {
    tm = bid / ntn; tn = bid % ntn;
  }
  const long row0 = tm * BM;
  const long col0 = tn * BN;

  const signed char* Ag = A + row0 * (long)K;
  const signed char* Bg = B + col0 * (long)K;

  // staging: chunk c = rows [c*32, c*32+32); wave w covers rows c*32+w*8..+8
  // (1 KiB per instr). HW: lane l -> base + l*16 = (row w*8+(l>>3), slot l&7).
  const int srow = wave * 8 + (lane >> 3);              // row within chunk
  const int kswz = ((lane & 7) ^ (lane >> 3)) * 16;     // pre-swizzled bytes

#define STAGE_A(c, kt) gload_lds16(Ag + (long)((c)*32 + srow) * K + (kt) + kswz, \
                                   &As[(c)*4096 + wave*1024])
#define STAGE_B(c, kt) gload_lds16(Bg + (long)((c)*32 + srow) * K + (kt) + kswz, \
                                   &Bs[(c)*4096 + wave*1024])
#define STAGE8(kt) { STAGE_B(0,kt); STAGE_B(1,kt); STAGE_B(2,kt); STAGE_B(3,kt); \
                     STAGE_A(0,kt); STAGE_A(1,kt); STAGE_A(2,kt); STAGE_A(3,kt); }

  const int rsel = lane & 15;     // fragment row (within 16)
  const int ksl  = lane >> 4;     // 0..3 -> 16B k-slot within a 64-elem half
  const int lan7 = lane & 7;      // == frag-row & 7 (bases are multiples of 16)

  i32x4 acc[4][4] = {};
  i32x4 bf[4][2];                 // B frags [n][kk]

#define AF_READ(m, kk)                                                          \
  (*(const i32x4*)&As[(wm*64 + (m)*16 + rsel)*BK                                \
                      + (((((kk)<<2)+ksl) ^ lan7) << 4)])

  const int NT = K / BK;   // 32 for this shape

  for (int t = 0; t < NT; ++t) {
    const long kt = (long)t * BK;
    STAGE8(kt)
    vmwait0();
    tile_barrier();          // all waves' stages landed

    __builtin_amdgcn_s_setprio(1);
    #pragma unroll
    for (int n = 0; n < 4; ++n)
      #pragma unroll
      for (int kk = 0; kk < 2; ++kk)
        bf[n][kk] = *(const i32x4*)&Bs[(wn*64 + n*16 + rsel)*BK
                                       + ((((kk<<2)+ksl) ^ lan7) << 4)];
    i32x4 afp0, afp1;
    afp0 = AF_READ(0, 0);
    #pragma unroll
    for (int f = 0; f < 8; ++f) {
      const int m = f & 3, kk = f >> 2;
      if (f < 7) {
        const int m2 = (f + 1) & 3, kk2 = (f + 1) >> 2;
        if (f & 1) afp0 = AF_READ(m2, kk2);
        else       afp1 = AF_READ(m2, kk2);
      }
      #pragma unroll
      for (int n = 0; n < 4; ++n)
        acc[m][n] = __builtin_amdgcn_mfma_i32_16x16x64_i8(
            (f & 1) ? afp1 : afp0, bf[n][kk], acc[m][n], 0, 0, 0);
    }
    __builtin_amdgcn_s_setprio(0);
    tile_barrier();          // WAR: reads done before next stage overwrites
  }
#undef AF_READ
#undef STAGE8
#undef STAGE_A
#undef STAGE_B

  // Epilogue. C/D layout (dtype-independent, m121-128): col = lane&15,
  // row = (lane>>4)*4 + j.  out = sx*sw*(acc - zp*rowsum) + bias.
  float swv[4], bvv[4]; int zpv[4];
  #pragma unroll
  for (int n = 0; n < 4; ++n) {
    const long gcol = col0 + wn * 64 + n * 16 + rsel;
    swv[n] = scale[gcol];
    bvv[n] = bias[gcol];
    zpv[n] = zp[gcol];
  }
  #pragma unroll
  for (int m = 0; m < 4; ++m) {
    const long growb = row0 + wm * 64 + m * 16 + ksl * 4;
    #pragma unroll
    for (int j = 0; j < 4; ++j) {
      const long grow = growb + j;
      const float sxv = sx[grow];
      const int   rsv = rowsum[grow];
      float* orow = C + grow * (long)N;
      #pragma unroll
      for (int n = 0; n < 4; ++n) {
        const long gcol = col0 + wn * 64 + n * 16 + rsel;
        orow[gcol] = (float)(acc[m][n][j] - zpv[n] * rsv) * (sxv * swv[n]) + bvv[n];
      }
    }
  }
}

// ---- fallback (ws too small / odd shape): reg-staged 128x128 bf16, inline dequant ----
__global__ __launch_bounds__(256)
void qlin_gemm_small(const float* __restrict__ Af, const int* __restrict__ Bi,
                     const int* __restrict__ zp,
                     const float* __restrict__ scale, const float* __restrict__ bias,
                     float* __restrict__ C, int M, int N, int K) {
  __shared__ alignas(16) __bf16 As[128 * 64];
  __shared__ alignas(16) __bf16 Bs[128 * 64];
  const int tid = threadIdx.x, wave = tid >> 6, lane = tid & 63;
  int bid = blockIdx.x, nwg = gridDim.x, swz = bid;
  if ((nwg & 7) == 0) swz = (bid & 7) * (nwg >> 3) + (bid >> 3);
  const int ntn = N / 128;
  const long row0 = (long)(swz / ntn) * 128, col0 = (long)(swz % ntn) * 128;
  const int wr = wave >> 1, wc = wave & 1;
  f32x4 acc[4][4] = {};
  for (int kt = 0; kt < K; kt += 64) {
    #pragma unroll
    for (int i = 0; i < 4; ++i) {
      const int flat = i * 2048 + tid * 8;
      const int r = flat >> 6, cc = flat & 63;
      const int wcc = ((cc >> 3) ^ (r & 7)) << 3;
      const float* g = Af + (row0 + r) * (long)K + kt + cc;
      float4 f0 = *(const float4*)g; float4 f1 = *(const float4*)(g + 4);
      bf16x8 v;
      v[0]=(__bf16)f0.x; v[1]=(__bf16)f0.y; v[2]=(__bf16)f0.z; v[3]=(__bf16)f0.w;
      v[4]=(__bf16)f1.x; v[5]=(__bf16)f1.y; v[6]=(__bf16)f1.z; v[7]=(__bf16)f1.w;
      *(bf16x8*)(As + r * 64 + wcc) = v;
    }
    #pragma unroll
    for (int i = 0; i < 4; ++i) {
      const int flat = i * 2048 + tid * 8;
      const int r = flat >> 6, cc = flat & 63;
      const int wcc = ((cc >> 3) ^ (r & 7)) << 3;
      const long grow = col0 + r;
      const int z = zp[grow];
      const int* g = Bi + grow * (long)K + kt + cc;
      int4 a = *(const int4*)g; int4 b = *(const int4*)(g + 4);
      bf16x8 v;
      v[0]=(__bf16)(float)(a.x-z); v[1]=(__bf16)(float)(a.y-z);
      v[2]=(__bf16)(float)(a.z-z); v[3]=(__bf16)(float)(a.w-z);
      v[4]=(__bf16)(float)(b.x-z); v[5]=(__bf16)(float)(b.y-z);
      v[6]=(__bf16)(float)(b.z-z); v[7]=(__bf16)(float)(b.w-z);
      *(bf16x8*)(Bs + r * 64 + wcc) = v;
    }
    __syncthreads();
    #pragma unroll
    for (int kk = 0; kk < 2; ++kk) {
      bf16x8 af[4], bfr[4];
      const int rs = lane & 15, ks = kk * 4 + (lane >> 4);
      const int rd = (ks ^ (lane & 7)) << 3;
      #pragma unroll
      for (int m = 0; m < 4; ++m) af[m] = *(const bf16x8*)(As + (wr*64 + m*16 + rs)*64 + rd);
      #pragma unroll
      for (int n = 0; n < 4; ++n) bfr[n] = *(const bf16x8*)(Bs + (wc*64 + n*16 + rs)*64 + rd);
      #pragma unroll
      for (int m = 0; m < 4; ++m)
        #pragma unroll
        for (int n = 0; n < 4; ++n)
          acc[m][n] = __builtin_amdgcn_mfma_f32_16x16x32_bf16(af[m], bfr[n], acc[m][n], 0, 0, 0);
    }
    __syncthreads();
  }
  #pragma unroll
  for (int m = 0; m < 4; ++m) {
    const long grow = row0 + wr * 64 + m * 16 + ((lane >> 4) << 2);
    #pragma unroll
    for (int n = 0; n < 4; ++n) {
      const long gcol = col0 + wc * 64 + n * 16 + (lane & 15);
      const float s = scale[gcol], bb2 = bias[gcol];
      float* o = C + grow * (long)N + gcol;
      #pragma unroll
      for (int j = 0; j < 4; ++j) o[(long)j * N] = acc[m][n][j] * s + bb2;
    }
  }
}

extern "C" void kernel_launch(void* const* d_in, const int* in_sizes, int n_in,
                              void* d_out, int out_size, void* d_ws, size_t ws_size,
                              hipStream_t stream) {
  const float* x    = (const float*)d_in[0];
  const int*   wint = (const int*)d_in[1];
  const float* wsc  = (const float*)d_in[2];
  const int*   wzp  = (const int*)d_in[3];
  const float* bias = (const float*)d_in[4];
  float* out = (float*)d_out;

  const int N = in_sizes[4];            // 16384 (OUT)
  const int K = in_sizes[1] / N;        // 4096  (IN)
  const int M = in_sizes[0] / K;        // 8192  (B*S)

  const size_t xqb = (size_t)M * K;             // int8 x
  const size_t wqb = (size_t)N * K;             // int8 w
  const size_t sxb = (size_t)M * sizeof(float);
  const size_t rsb = (size_t)M * sizeof(int);
  const int NT = K / BK;
  const long nk = (long)N * K;

  if (ws_size >= xqb + wqb + sxb + rsb && (M % BM) == 0 && (N % BN) == 0 &&
      (K % BK) == 0 && (K % 4096) == 0 && NT >= 2 && (nk % 4096) == 0) {
    signed char* xq = (signed char*)d_ws;
    signed char* wq = xq + xqb;
    float* sx  = (float*)(wq + wqb);
    int* rsum  = (int*)((char*)sx + sxb);
    const int wblocks = (int)(nk / 4096);
    prep_kernel<<<M + wblocks, 256, 0, stream>>>(x, xq, sx, rsum,
                                                 wint, wzp, wq, M, K);
    const int grid = (M / BM) * (N / BN); // 64 * 128 = 8192
    qlin_gemm_i8<<<grid, THREADS, 0, stream>>>(xq, wq, sx, rsum, wzp, wsc, bias,
                                               out, M, N, K);
  } else {
    const int grid = (M / 128) * (N / 128);
    qlin_gemm_small<<<grid, 256, 0, stream>>>(x, wint, wzp, wsc, bias, out, M, N, K);
  }
}